// Round 9
// baseline (465.791 us; speedup 1.0000x reference)
//
#include <hip/hip_runtime.h>
#include <hip/hip_bf16.h>
#include <math.h>

typedef __hip_bfloat16 bf16;
typedef __attribute__((ext_vector_type(8))) short short8;  // 8 bf16 = 4 VGPRs
typedef __attribute__((ext_vector_type(4))) float f32x4;

#define SEQ   2048
#define NPOS  4095          // 2*SEQ-1
#define DIMM  768
#define HEADS 8
#define DK    64
#define HD    512           // HEADS*DK
#define BATCH 2
#define BH    16            // BATCH*HEADS
#define ROWS  4096          // BATCH*SEQ

// ---------------- workspace layout (BYTE offsets), ~44.4 MB ----------------
#define OB_RELK  ((size_t)0)                      // bf16 [8][4095][64] (+pad)
#define OB_QC    ((size_t)4194304)
#define OB_QP    ((size_t)8388608)
#define OB_K     ((size_t)12582912)
#define OB_V     ((size_t)16777216)
#define OB_OH    ((size_t)20971520)               // bf16 [4096][512]
// aliased (disjoint lifetimes):
#define OB_EMBH  OB_OH                            // dead after relk_gemm
#define OB_EMBL  ((size_t)(OB_OH + 1572864))
#define OB_VT    OB_OH                            // V^T [16][64][2048] bf16, dead before merge writes oh
#define OB_XH    ((size_t)25165824)               // dead after qkv_gemm
#define OB_XL    ((size_t)31457280)
#define OB_WQKVH ((size_t)37748736)               // dead after qkv_gemm
#define OB_WQKVL ((size_t)40108032)
#define OB_OP    ((size_t)25165824)               // f32 [2][16][2048][64] partial O (over dead x/wqkv)
#define OB_LP    ((size_t)41943040)               // f32 [2][16][2048] partial l
#define OB_WOH   ((size_t)42467328)               // out-proj weights (live until out_gemm)
#define OB_WOL   ((size_t)43253760)
#define OB_WRH   ((size_t)44040192)
#define OB_WRL   ((size_t)44236800)

// RNE float -> bf16 bits (finite inputs only)
__device__ __forceinline__ unsigned f2bf(float f) {
  unsigned u = __float_as_uint(f);
  return (u + 0x7fffu + ((u >> 16) & 1u)) >> 16;
}
__device__ __forceinline__ void split2(float v, unsigned& hb, unsigned& lb) {
  hb = f2bf(v);
  const float back = __uint_as_float(hb << 16);
  lb = f2bf(v - back);
}

// ---------------- 1. positional embedding -> split bf16 ----------------
__global__ void pos_emb_kernel(short* __restrict__ eh, short* __restrict__ el) {
  const int row = blockIdx.x * 2 + (threadIdx.x >> 5);
  const int j   = threadIdx.x & 31;
  if (row >= NPOS) {
    for (int c = j; c < 192; c += 32) { eh[(size_t)row * 192 + c] = 0; el[(size_t)row * 192 + c] = 0; }
    return;
  }
  const float dist = (float)(row - (SEQ - 1));
  const float ad   = fabsf(dist);

  const float hl    = exp2f(3.0f + 8.0f * (float)j / 31.0f);
  const float f_exp = exp2f(-ad / hl);

  const float width = exp2f((float)(j + 1)) - 1.0f;
  const float f_cm  = (width > ad) ? 1.0f : 0.0f;

  float prob;
  if (ad > 0.0f) {
    const float c   = 4.0f * (float)((j + 1) * (j + 1));
    const float r   = (float)(j + 1) / 16.0f;
    const float lu  = (c - 1.0f) * logf(ad) - r * ad;
    const float ln_ = lgammaf(c) - c * logf(r);
    prob = expf(lu - ln_) + 1e-8f;
  } else {
    prob = 1e-8f;
  }
  float mx = prob;
  for (int off = 16; off; off >>= 1) mx = fmaxf(mx, __shfl_xor(mx, off, 32));
  const float f_g = prob / mx;

  const float s = (dist > 0.f) ? 1.f : ((dist < 0.f) ? -1.f : 0.f);
  const float vals[6] = {f_exp, f_cm, f_g, s * f_exp, s * f_cm, s * f_g};
  short* ph = eh + (size_t)row * 192;
  short* pl = el + (size_t)row * 192;
#pragma unroll
  for (int q = 0; q < 6; q++) {
    unsigned hb, lb;
    split2(vals[q], hb, lb);
    ph[q * 32 + j] = (short)hb;
    pl[q * 32 + j] = (short)lb;
  }
}

// ---------------- 2a. x fp32 -> split bf16 ----------------
__global__ void conv_split(const float* __restrict__ src, short* __restrict__ dh,
                           short* __restrict__ dl, int n4) {
  const int i = blockIdx.x * 256 + threadIdx.x;
  if (i >= n4) return;
  const float4 v = ((const float4*)src)[i];
  unsigned h0, l0, h1, l1, h2, l2, h3, l3;
  split2(v.x, h0, l0); split2(v.y, h1, l1); split2(v.z, h2, l2); split2(v.w, h3, l3);
  *(uint2*)&dh[(size_t)i * 4] = make_uint2(h0 | (h1 << 16), h2 | (h3 << 16));
  *(uint2*)&dl[(size_t)i * 4] = make_uint2(l0 | (l1 << 16), l2 | (l3 << 16));
}

// ---------------- 2b. transpose fp32 [R][C] -> split bf16 [C][R] ----------------
__global__ void transpose_split(const float* __restrict__ src, short* __restrict__ dh,
                                short* __restrict__ dl, int R, int C) {
  __shared__ float tile[32][33];
  const int t = threadIdx.x;
  const int c0 = blockIdx.x * 32, r0 = blockIdx.y * 32;
  {
    const int lr = t >> 3, lc = (t & 7) * 4;
    const float4 v = *(const float4*)&src[(size_t)(r0 + lr) * C + c0 + lc];
    tile[lr][lc] = v.x; tile[lr][lc + 1] = v.y; tile[lr][lc + 2] = v.z; tile[lr][lc + 3] = v.w;
  }
  __syncthreads();
  const int nn = t >> 3, kb = (t & 7) * 4;
  unsigned hb[4], lb[4];
#pragma unroll
  for (int e = 0; e < 4; e++) split2(tile[kb + e][nn], hb[e], lb[e]);
  const size_t o = (size_t)(c0 + nn) * R + r0 + kb;
  *(uint2*)&dh[o] = make_uint2(hb[0] | (hb[1] << 16), hb[2] | (hb[3] << 16));
  *(uint2*)&dl[o] = make_uint2(lb[0] | (lb[1] << 16), lb[2] | (lb[3] << 16));
}

// ---------------- 2c. V transpose: vv [bh][s][64] -> vt [bh][64][2048] ----------------
__global__ void vtrans_kernel(const short* __restrict__ vv, short* __restrict__ vt) {
  __shared__ short tile[64][72];
  const int t = threadIdx.x;
  const int s0 = blockIdx.x * 64, bh = blockIdx.y;
  {
    const int sl = t >> 2, dc = (t & 3) * 16;
    const short* src = vv + ((size_t)bh * SEQ + s0 + sl) * DK + dc;
    *(uint4*)&tile[sl][dc]     = *(const uint4*)src;
    *(uint4*)&tile[sl][dc + 8] = *(const uint4*)(src + 8);
  }
  __syncthreads();
  const int dr = t >> 6, sc = t & 63;
#pragma unroll
  for (int it = 0; it < 16; it++) {
    const int d = it * 4 + dr;
    vt[((size_t)bh * DK + d) * SEQ + s0 + sc] = tile[sc][d];
  }
}

// ---------------- 3. tiled split-bf16 MFMA GEMM, 128x128 tile, BK=32, prefetched ----------------
template <int EPI, int SPLITA, int KDIM>
__global__ __launch_bounds__(256) void gemm128(
    const short* __restrict__ Ah, const short* __restrict__ Al,
    const short* __restrict__ Bhp, const short* __restrict__ Blp,
    const float* __restrict__ cb, const float* __restrict__ pb,
    const float* __restrict__ bias,
    bf16* __restrict__ oq, bf16* __restrict__ oqp,
    bf16* __restrict__ ok, bf16* __restrict__ ov,
    float* __restrict__ ofp) {
  __shared__ short AsH[128][40];
  __shared__ short AsL[SPLITA ? 128 : 1][40];
  __shared__ short BsH[128][40];
  __shared__ short BsL[128][40];

  const int t = threadIdx.x, lane = t & 63, w = t >> 6;
  const int quad = lane >> 4, l15 = lane & 15;
  const int wm = (w >> 1) * 64, wn = (w & 1) * 64;
  const int m0 = blockIdx.x * 128, n0 = blockIdx.y * 128;

  const int sr = t >> 1;
  const int sc = (t & 1) * 16;

  f32x4 acc[4][4];
#pragma unroll
  for (int i = 0; i < 4; i++)
#pragma unroll
    for (int j = 0; j < 4; j++) acc[i][j] = (f32x4){0.f, 0.f, 0.f, 0.f};

  // prologue: prefetch k0=0 staging into registers
  uint4 sA[2], sAl[2], sB[2], sBl[2];
  {
    const size_t ga = (size_t)(m0 + sr) * KDIM + sc;
    sA[0] = *(const uint4*)&Ah[ga]; sA[1] = *(const uint4*)&Ah[ga + 8];
    if (SPLITA) { sAl[0] = *(const uint4*)&Al[ga]; sAl[1] = *(const uint4*)&Al[ga + 8]; }
    const size_t gb = (size_t)(n0 + sr) * KDIM + sc;
    sB[0] = *(const uint4*)&Bhp[gb]; sB[1] = *(const uint4*)&Bhp[gb + 8];
    sBl[0] = *(const uint4*)&Blp[gb]; sBl[1] = *(const uint4*)&Blp[gb + 8];
  }

  for (int k0 = 0; k0 < KDIM; k0 += 32) {
    __syncthreads();
    *(uint4*)&AsH[sr][sc]     = sA[0];
    *(uint4*)&AsH[sr][sc + 8] = sA[1];
    if (SPLITA) {
      *(uint4*)&AsL[sr][sc]     = sAl[0];
      *(uint4*)&AsL[sr][sc + 8] = sAl[1];
    }
    *(uint4*)&BsH[sr][sc]     = sB[0];
    *(uint4*)&BsH[sr][sc + 8] = sB[1];
    *(uint4*)&BsL[sr][sc]     = sBl[0];
    *(uint4*)&BsL[sr][sc + 8] = sBl[1];
    __syncthreads();

    // prefetch next slab while computing this one
    if (k0 + 32 < KDIM) {
      const size_t ga = (size_t)(m0 + sr) * KDIM + k0 + 32 + sc;
      sA[0] = *(const uint4*)&Ah[ga]; sA[1] = *(const uint4*)&Ah[ga + 8];
      if (SPLITA) { sAl[0] = *(const uint4*)&Al[ga]; sAl[1] = *(const uint4*)&Al[ga + 8]; }
      const size_t gb = (size_t)(n0 + sr) * KDIM + k0 + 32 + sc;
      sB[0] = *(const uint4*)&Bhp[gb]; sB[1] = *(const uint4*)&Bhp[gb + 8];
      sBl[0] = *(const uint4*)&Blp[gb]; sBl[1] = *(const uint4*)&Blp[gb + 8];
    }

    short8 amh[4], aml[4], bnh[4], bnl[4];
#pragma unroll
    for (int i = 0; i < 4; i++) {
      amh[i] = *(const short8*)&AsH[wm + i * 16 + l15][quad * 8];
      if (SPLITA) aml[i] = *(const short8*)&AsL[wm + i * 16 + l15][quad * 8];
      bnh[i] = *(const short8*)&BsH[wn + i * 16 + l15][quad * 8];
      bnl[i] = *(const short8*)&BsL[wn + i * 16 + l15][quad * 8];
    }
#pragma unroll
    for (int i = 0; i < 4; i++) {
#pragma unroll
      for (int j = 0; j < 4; j++) {
        acc[i][j] = __builtin_amdgcn_mfma_f32_16x16x32_bf16(amh[i], bnh[j], acc[i][j], 0, 0, 0);
        acc[i][j] = __builtin_amdgcn_mfma_f32_16x16x32_bf16(amh[i], bnl[j], acc[i][j], 0, 0, 0);
        if (SPLITA)
          acc[i][j] = __builtin_amdgcn_mfma_f32_16x16x32_bf16(aml[i], bnh[j], acc[i][j], 0, 0, 0);
      }
    }
  }

  const int sel = (EPI == 0) ? (int)(blockIdx.y >> 2) : 0;
#pragma unroll
  for (int i = 0; i < 4; i++) {
#pragma unroll
    for (int j = 0; j < 4; j++) {
      const int n = n0 + wn + j * 16 + l15;
#pragma unroll
      for (int g = 0; g < 4; g++) {
        const int m = m0 + wm + i * 16 + quad * 4 + g;
        const float v = acc[i][j][g];
        if (EPI == 0) {
          const int hd_ = n & 511, hh = hd_ >> 6, d = hd_ & 63;
          const int b = m >> 11, s = m & 2047;
          const size_t idx = (((size_t)(b * HEADS + hh) * SEQ) + s) * DK + d;
          if (sel == 0) {
            const float sv = v * 0.125f;
            oq[idx]  = __float2bfloat16(sv + cb[hh * DK + d]);
            oqp[idx] = __float2bfloat16(sv + pb[hh * DK + d]);
          } else if (sel == 1) {
            ok[idx] = __float2bfloat16(v);
          } else {
            ov[idx] = __float2bfloat16(v);
          }
        } else if (EPI == 1) {
          const int hh = n >> 6, d = n & 63;
          if (m < NPOS) oq[((size_t)hh * NPOS + m) * DK + d] = __float2bfloat16(v);
        } else {
          ofp[(size_t)m * DIMM + n] = v + bias[n];
        }
      }
    }
  }
}

// ---------------- 4. no-max attention, register-prefetched ----------------
// grid (SEQ/64, BH, 2), block 256 = 4 waves. K frags + rel staging prefetched one
// iteration ahead in registers; V loaded at iter top (consumed ~600cyc later).
__global__ __launch_bounds__(256, 3) void attn_mfma3(
    const short* __restrict__ qc, const short* __restrict__ qp,
    const short* __restrict__ kg, const short* __restrict__ vt,
    const short* __restrict__ relk,
    float* __restrict__ Op, float* __restrict__ Lp) {
  __shared__ short Rel_lds[128][72];     // block's rel window (128 rows)
  __shared__ short Pw[4][16][72];        // per-wave P in A-layout

  const int t    = threadIdx.x;
  const int lane = t & 63;
  const int w    = t >> 6;
  const int quad = lane >> 4;
  const int l15  = lane & 15;
  const int bh   = blockIdx.y;
  const int h    = bh & 7;
  const int i0   = blockIdx.x * 64;
  const int z    = blockIdx.z;
  const int jb   = z * (SEQ / 2);

  short8 qcA[2], qpA[2];
  {
    const size_t qrow = ((size_t)bh * SEQ + i0 + w * 16 + l15) * DK + quad * 8;
    qcA[0] = *(const short8*)(qc + qrow);
    qcA[1] = *(const short8*)(qc + qrow + 32);
    qpA[0] = *(const short8*)(qp + qrow);
    qpA[1] = *(const short8*)(qp + qrow + 32);
  }

  int idxg[4]; bool selg[4];
#pragma unroll
  for (int g = 0; g < 4; g++) {
    const int r = quad * 4 + g;
    idxg[g] = (((lane & 48) | ((l15 + 15 - r) & 15)) << 2);
    selg[g] = (l15 <= r);
  }

  short8 ones8;
#pragma unroll
  for (int e = 0; e < 8; e++) ones8[e] = (short)0x3F80;   // bf16 1.0

  f32x4 oacc[4];
#pragma unroll
  for (int dt = 0; dt < 4; dt++) oacc[dt] = (f32x4){0.f, 0.f, 0.f, 0.f};
  f32x4 lacc = (f32x4){0.f, 0.f, 0.f, 0.f};

  const short* kbase = kg + (size_t)bh * SEQ * DK;
  const short* vbase = vt + (size_t)bh * DK * SEQ;
  const short* rbase = relk + (size_t)h * NPOS * DK;

  const int rr  = t >> 1, rcc = (t & 1) * 32;   // rel staging assignment
  const int rb_w = 48 - 16 * w;                 // wave's window base in Rel_lds

  // ---- prologue prefetch: K frags + rel staging for jt=0 ----
  short8 kf[4][2];
  uint4 rstg[4];
  {
#pragma unroll
    for (int nt = 0; nt < 4; nt++) {
      const short* kr = kbase + (size_t)(jb + nt * 16 + l15) * DK + quad * 8;
      kf[nt][0] = *(const short8*)kr;
      kf[nt][1] = *(const short8*)(kr + 32);
    }
    const short* src = rbase + (size_t)((jb - i0 + 1984) + rr) * DK + rcc;
    rstg[0] = *(const uint4*)(src);
    rstg[1] = *(const uint4*)(src + 8);
    rstg[2] = *(const uint4*)(src + 16);
    rstg[3] = *(const uint4*)(src + 24);
  }

  for (int jt = 0; jt < SEQ / 2 / 64; jt++) {
    const int j0 = jb + jt * 64;

    __syncthreads();
    *(uint4*)&Rel_lds[rr][rcc]      = rstg[0];
    *(uint4*)&Rel_lds[rr][rcc + 8]  = rstg[1];
    *(uint4*)&Rel_lds[rr][rcc + 16] = rstg[2];
    *(uint4*)&Rel_lds[rr][rcc + 24] = rstg[3];
    __syncthreads();

    // ---- V loads for THIS tile (consumed at iteration end) ----
    short8 vf[4][2];
#pragma unroll
    for (int dt = 0; dt < 4; dt++) {
      const short* vr = vbase + (size_t)(dt * 16 + l15) * SEQ + j0 + quad * 8;
      vf[dt][0] = *(const short8*)vr;
      vf[dt][1] = *(const short8*)(vr + 32);
    }

    // ---- content S = Qc . K^T from prefetched K frags ----
    f32x4 sacc[4];
#pragma unroll
    for (int nt = 0; nt < 4; nt++) {
      f32x4 a = (f32x4){0.f, 0.f, 0.f, 0.f};
      a = __builtin_amdgcn_mfma_f32_16x16x32_bf16(qcA[0], kf[nt][0], a, 0, 0, 0);
      a = __builtin_amdgcn_mfma_f32_16x16x32_bf16(qcA[1], kf[nt][1], a, 0, 0, 0);
      sacc[nt] = a;
    }

    // ---- prefetch NEXT tile's K frags + rel staging (used next iteration) ----
    if (jt + 1 < SEQ / 2 / 64) {
      const int j1 = j0 + 64;
#pragma unroll
      for (int nt = 0; nt < 4; nt++) {
        const short* kr = kbase + (size_t)(j1 + nt * 16 + l15) * DK + quad * 8;
        kf[nt][0] = *(const short8*)kr;
        kf[nt][1] = *(const short8*)(kr + 32);
      }
      const short* src = rbase + (size_t)((j1 - i0 + 1984) + rr) * DK + rcc;
      rstg[0] = *(const uint4*)(src);
      rstg[1] = *(const uint4*)(src + 8);
      rstg[2] = *(const uint4*)(src + 16);
      rstg[3] = *(const uint4*)(src + 24);
    }

    // ---- rel logits (LDS B-frags) -> rolling bpermute shift -> exp -> Pw ----
    f32x4 rprev;
    {
      const short* rl = &Rel_lds[rb_w + l15][quad * 8];
      short8 b0 = *(const short8*)rl;
      short8 b1 = *(const short8*)(rl + 32);
      f32x4 a = (f32x4){0.f, 0.f, 0.f, 0.f};
      a = __builtin_amdgcn_mfma_f32_16x16x32_bf16(qpA[0], b0, a, 0, 0, 0);
      a = __builtin_amdgcn_mfma_f32_16x16x32_bf16(qpA[1], b1, a, 0, 0, 0);
      rprev = a;
    }
    f32x4 bpp;
#pragma unroll
    for (int g = 0; g < 4; g++)
      bpp[g] = __int_as_float(__builtin_amdgcn_ds_bpermute(idxg[g], __float_as_int(rprev[g])));

#pragma unroll
    for (int nt = 0; nt < 4; nt++) {
      f32x4 rcur;
      {
        const short* rl = &Rel_lds[rb_w + (nt + 1) * 16 + l15][quad * 8];
        short8 b0 = *(const short8*)rl;
        short8 b1 = *(const short8*)(rl + 32);
        f32x4 a = (f32x4){0.f, 0.f, 0.f, 0.f};
        a = __builtin_amdgcn_mfma_f32_16x16x32_bf16(qpA[0], b0, a, 0, 0, 0);
        a = __builtin_amdgcn_mfma_f32_16x16x32_bf16(qpA[1], b1, a, 0, 0, 0);
        rcur = a;
      }
      f32x4 bpc;
#pragma unroll
      for (int g = 0; g < 4; g++)
        bpc[g] = __int_as_float(__builtin_amdgcn_ds_bpermute(idxg[g], __float_as_int(rcur[g])));
#pragma unroll
      for (int g = 0; g < 4; g++) {
        const float relv = selg[g] ? bpp[g] : bpc[g];
        const float s = sacc[nt][g] + relv;
        const float p = __expf(s - 12.0f);
        Pw[w][quad * 4 + g][nt * 16 + l15] = (short)f2bf(p);
      }
      bpp = bpc;
    }

    // ---- PV + row-sum from prefetched V frags; Pw wave-private ----
#pragma unroll
    for (int ks = 0; ks < 2; ks++) {
      short8 pA = *(const short8*)&Pw[w][l15][ks * 32 + quad * 8];
      lacc = __builtin_amdgcn_mfma_f32_16x16x32_bf16(pA, ones8, lacc, 0, 0, 0);
#pragma unroll
      for (int dt = 0; dt < 4; dt++) {
        oacc[dt] = __builtin_amdgcn_mfma_f32_16x16x32_bf16(pA, vf[dt][ks], oacc[dt], 0, 0, 0);
      }
    }
  }

  // ---- epilogue: store partial O (unnormalized) and l ----
  const size_t obase = ((size_t)(z * BH + bh) * SEQ + i0 + w * 16);
#pragma unroll
  for (int g = 0; g < 4; g++) {
    const int r = quad * 4 + g;
#pragma unroll
    for (int dt = 0; dt < 4; dt++)
      Op[(obase + r) * DK + dt * 16 + l15] = oacc[dt][g];
    if (l15 == 0) Lp[obase + r] = lacc[g];
  }
}

// ---------------- 5. merge halves -> oh bf16 ----------------
__global__ void merge_kernel(const float* __restrict__ Op, const float* __restrict__ Lp,
                             bf16* __restrict__ oh) {
  const int gid = blockIdx.x * 256 + threadIdx.x;
  const int m = gid >> 7;
  const int n0 = (gid & 127) * 4;
  const int b = m >> 11, s = m & 2047;
  const int hh = n0 >> 6, d0 = n0 & 63;
  const int bh = b * HEADS + hh;
  const float l = Lp[(size_t)bh * SEQ + s] + Lp[((size_t)BH + bh) * SEQ + s];
  const float inv = 1.0f / l;
  const float4 o0 = *(const float4*)&Op[((size_t)bh * SEQ + s) * DK + d0];
  const float4 o1 = *(const float4*)&Op[(((size_t)BH + bh) * SEQ + s) * DK + d0];
  *(uint2*)&oh[(size_t)m * HD + n0] = make_uint2(
      f2bf((o0.x + o1.x) * inv) | (f2bf((o0.y + o1.y) * inv) << 16),
      f2bf((o0.z + o1.z) * inv) | (f2bf((o0.w + o1.w) * inv) << 16));
}

// ---------------- launch ----------------
extern "C" void kernel_launch(void* const* d_in, const int* in_sizes, int n_in,
                              void* d_out, int out_size, void* d_ws, size_t ws_size,
                              hipStream_t stream) {
  (void)in_sizes; (void)n_in; (void)out_size; (void)ws_size;
  const float* x    = (const float*)d_in[0];
  const float* Wq   = (const float*)d_in[1];
  const float* Wk   = (const float*)d_in[2];
  const float* Wv   = (const float*)d_in[3];
  const float* Wrel = (const float*)d_in[4];
  const float* Wout = (const float*)d_in[5];
  const float* bout = (const float*)d_in[6];
  const float* cb   = (const float*)d_in[7];
  const float* pb   = (const float*)d_in[8];
  float* out = (float*)d_out;

  char* ws = (char*)d_ws;
  bf16*  relk = (bf16*)(ws + OB_RELK);
  bf16*  qc   = (bf16*)(ws + OB_QC);
  bf16*  qp   = (bf16*)(ws + OB_QP);
  bf16*  kk   = (bf16*)(ws + OB_K);
  bf16*  vv   = (bf16*)(ws + OB_V);
  bf16*  oh   = (bf16*)(ws + OB_OH);
  short* vt   = (short*)(ws + OB_VT);
  float* Opb  = (float*)(ws + OB_OP);
  float* Lpb  = (float*)(ws + OB_LP);
  short* embh = (short*)(ws + OB_EMBH);
  short* embl = (short*)(ws + OB_EMBL);
  short* xh   = (short*)(ws + OB_XH);
  short* xl   = (short*)(ws + OB_XL);
  short* wqh  = (short*)(ws + OB_WQKVH);
  short* wql  = (short*)(ws + OB_WQKVL);
  short* woh  = (short*)(ws + OB_WOH);
  short* wol  = (short*)(ws + OB_WOL);
  short* wrh  = (short*)(ws + OB_WRH);
  short* wrl  = (short*)(ws + OB_WRL);

  hipLaunchKernelGGL(pos_emb_kernel, dim3(2048), dim3(64), 0, stream, embh, embl);
  hipLaunchKernelGGL(conv_split, dim3(3072), dim3(256), 0, stream, x, xh, xl, ROWS * DIMM / 4);
  hipLaunchKernelGGL(transpose_split, dim3(16, 24), dim3(256), 0, stream, Wq,   wqh,                wql,                DIMM, HD);
  hipLaunchKernelGGL(transpose_split, dim3(16, 24), dim3(256), 0, stream, Wk,   wqh + 512 * DIMM,   wql + 512 * DIMM,   DIMM, HD);
  hipLaunchKernelGGL(transpose_split, dim3(16, 24), dim3(256), 0, stream, Wv,   wqh + 1024 * DIMM,  wql + 1024 * DIMM,  DIMM, HD);
  hipLaunchKernelGGL(transpose_split, dim3(24, 16), dim3(256), 0, stream, Wout, woh,                wol,                HD,   DIMM);
  hipLaunchKernelGGL(transpose_split, dim3(16, 6),  dim3(256), 0, stream, Wrel, wrh,                wrl,                192,  HD);

  hipLaunchKernelGGL((gemm128<1, 1, 192>), dim3(32, 4), dim3(256), 0, stream,
                     embh, embl, wrh, wrl, nullptr, nullptr, nullptr,
                     relk, nullptr, nullptr, nullptr, nullptr);
  hipLaunchKernelGGL((gemm128<0, 1, DIMM>), dim3(32, 12), dim3(256), 0, stream,
                     xh, xl, wqh, wql, cb, pb, nullptr,
                     qc, qp, kk, vv, nullptr);
  hipLaunchKernelGGL(vtrans_kernel, dim3(SEQ / 64, BH), dim3(256), 0, stream,
                     (const short*)vv, vt);
  hipLaunchKernelGGL(attn_mfma3, dim3(SEQ / 64, BH, 2), dim3(256), 0, stream,
                     (const short*)qc, (const short*)qp, (const short*)kk,
                     (const short*)vt, (const short*)relk, Opb, Lpb);
  hipLaunchKernelGGL(merge_kernel, dim3(ROWS * (HD / 4) / 256), dim3(256), 0, stream,
                     Opb, Lpb, oh);
  hipLaunchKernelGGL((gemm128<2, 0, HD>), dim3(32, 6), dim3(256), 0, stream,
                     (const short*)oh, nullptr, woh, wol, nullptr, nullptr, bout,
                     nullptr, nullptr, nullptr, nullptr, out);
}

// Round 10
// 271.193 us; speedup vs baseline: 1.7176x; 1.7176x over previous
//
#include <hip/hip_runtime.h>
#include <hip/hip_bf16.h>
#include <math.h>

typedef __hip_bfloat16 bf16;
typedef __attribute__((ext_vector_type(8))) short short8;  // 8 bf16 = 4 VGPRs
typedef __attribute__((ext_vector_type(4))) float f32x4;

#define SEQ   2048
#define NPOS  4095          // 2*SEQ-1
#define DIMM  768
#define HEADS 8
#define DK    64
#define HD    512           // HEADS*DK
#define BATCH 2
#define BH    16            // BATCH*HEADS
#define ROWS  4096          // BATCH*SEQ

// ---------------- workspace layout (BYTE offsets), ~44.4 MB ----------------
#define OB_RELK  ((size_t)0)                      // bf16 [8][4095][64] (+pad)
#define OB_QC    ((size_t)4194304)
#define OB_QP    ((size_t)8388608)
#define OB_K     ((size_t)12582912)
#define OB_V     ((size_t)16777216)
#define OB_OH    ((size_t)20971520)               // bf16 [4096][512]
// aliased (disjoint lifetimes):
#define OB_EMBH  OB_OH                            // dead after relk_gemm
#define OB_EMBL  ((size_t)(OB_OH + 1572864))
#define OB_VT    OB_OH                            // V^T [16][64][2048] bf16, dead before merge writes oh
#define OB_XH    ((size_t)25165824)               // dead after qkv_gemm
#define OB_XL    ((size_t)31457280)
#define OB_WQKVH ((size_t)37748736)               // dead after qkv_gemm
#define OB_WQKVL ((size_t)40108032)
#define OB_OP    ((size_t)25165824)               // f32 [2][16][2048][64] partial O (over dead x/wqkv)
#define OB_LP    ((size_t)41943040)               // f32 [2][16][2048] partial l
#define OB_WOH   ((size_t)42467328)               // out-proj weights (live until out_gemm)
#define OB_WOL   ((size_t)43253760)
#define OB_WRH   ((size_t)44040192)
#define OB_WRL   ((size_t)44236800)

// RNE float -> bf16 bits (finite inputs only)
__device__ __forceinline__ unsigned f2bf(float f) {
  unsigned u = __float_as_uint(f);
  return (u + 0x7fffu + ((u >> 16) & 1u)) >> 16;
}
__device__ __forceinline__ void split2(float v, unsigned& hb, unsigned& lb) {
  hb = f2bf(v);
  const float back = __uint_as_float(hb << 16);
  lb = f2bf(v - back);
}

// ---------------- 1. positional embedding -> split bf16 ----------------
__global__ void pos_emb_kernel(short* __restrict__ eh, short* __restrict__ el) {
  const int row = blockIdx.x * 2 + (threadIdx.x >> 5);
  const int j   = threadIdx.x & 31;
  if (row >= NPOS) {
    for (int c = j; c < 192; c += 32) { eh[(size_t)row * 192 + c] = 0; el[(size_t)row * 192 + c] = 0; }
    return;
  }
  const float dist = (float)(row - (SEQ - 1));
  const float ad   = fabsf(dist);

  const float hl    = exp2f(3.0f + 8.0f * (float)j / 31.0f);
  const float f_exp = exp2f(-ad / hl);

  const float width = exp2f((float)(j + 1)) - 1.0f;
  const float f_cm  = (width > ad) ? 1.0f : 0.0f;

  float prob;
  if (ad > 0.0f) {
    const float c   = 4.0f * (float)((j + 1) * (j + 1));
    const float r   = (float)(j + 1) / 16.0f;
    const float lu  = (c - 1.0f) * logf(ad) - r * ad;
    const float ln_ = lgammaf(c) - c * logf(r);
    prob = expf(lu - ln_) + 1e-8f;
  } else {
    prob = 1e-8f;
  }
  float mx = prob;
  for (int off = 16; off; off >>= 1) mx = fmaxf(mx, __shfl_xor(mx, off, 32));
  const float f_g = prob / mx;

  const float s = (dist > 0.f) ? 1.f : ((dist < 0.f) ? -1.f : 0.f);
  const float vals[6] = {f_exp, f_cm, f_g, s * f_exp, s * f_cm, s * f_g};
  short* ph = eh + (size_t)row * 192;
  short* pl = el + (size_t)row * 192;
#pragma unroll
  for (int q = 0; q < 6; q++) {
    unsigned hb, lb;
    split2(vals[q], hb, lb);
    ph[q * 32 + j] = (short)hb;
    pl[q * 32 + j] = (short)lb;
  }
}

// ---------------- 2a. x fp32 -> split bf16 ----------------
__global__ void conv_split(const float* __restrict__ src, short* __restrict__ dh,
                           short* __restrict__ dl, int n4) {
  const int i = blockIdx.x * 256 + threadIdx.x;
  if (i >= n4) return;
  const float4 v = ((const float4*)src)[i];
  unsigned h0, l0, h1, l1, h2, l2, h3, l3;
  split2(v.x, h0, l0); split2(v.y, h1, l1); split2(v.z, h2, l2); split2(v.w, h3, l3);
  *(uint2*)&dh[(size_t)i * 4] = make_uint2(h0 | (h1 << 16), h2 | (h3 << 16));
  *(uint2*)&dl[(size_t)i * 4] = make_uint2(l0 | (l1 << 16), l2 | (l3 << 16));
}

// ---------------- 2b. transpose fp32 [R][C] -> split bf16 [C][R] ----------------
__global__ void transpose_split(const float* __restrict__ src, short* __restrict__ dh,
                                short* __restrict__ dl, int R, int C) {
  __shared__ float tile[32][33];
  const int t = threadIdx.x;
  const int c0 = blockIdx.x * 32, r0 = blockIdx.y * 32;
  {
    const int lr = t >> 3, lc = (t & 7) * 4;
    const float4 v = *(const float4*)&src[(size_t)(r0 + lr) * C + c0 + lc];
    tile[lr][lc] = v.x; tile[lr][lc + 1] = v.y; tile[lr][lc + 2] = v.z; tile[lr][lc + 3] = v.w;
  }
  __syncthreads();
  const int nn = t >> 3, kb = (t & 7) * 4;
  unsigned hb[4], lb[4];
#pragma unroll
  for (int e = 0; e < 4; e++) split2(tile[kb + e][nn], hb[e], lb[e]);
  const size_t o = (size_t)(c0 + nn) * R + r0 + kb;
  *(uint2*)&dh[o] = make_uint2(hb[0] | (hb[1] << 16), hb[2] | (hb[3] << 16));
  *(uint2*)&dl[o] = make_uint2(lb[0] | (lb[1] << 16), lb[2] | (lb[3] << 16));
}

// ---------------- 2c. V transpose: vv [bh][s][64] -> vt [bh][64][2048] ----------------
__global__ void vtrans_kernel(const short* __restrict__ vv, short* __restrict__ vt) {
  __shared__ short tile[64][72];
  const int t = threadIdx.x;
  const int s0 = blockIdx.x * 64, bh = blockIdx.y;
  {
    const int sl = t >> 2, dc = (t & 3) * 16;
    const short* src = vv + ((size_t)bh * SEQ + s0 + sl) * DK + dc;
    *(uint4*)&tile[sl][dc]     = *(const uint4*)src;
    *(uint4*)&tile[sl][dc + 8] = *(const uint4*)(src + 8);
  }
  __syncthreads();
  const int dr = t >> 6, sc = t & 63;
#pragma unroll
  for (int it = 0; it < 16; it++) {
    const int d = it * 4 + dr;
    vt[((size_t)bh * DK + d) * SEQ + s0 + sc] = tile[sc][d];
  }
}

// ---------------- 3. tiled split-bf16 MFMA GEMM, 128x128 tile, BK=32 ----------------
template <int EPI, int SPLITA, int KDIM>
__global__ __launch_bounds__(256) void gemm128(
    const short* __restrict__ Ah, const short* __restrict__ Al,
    const short* __restrict__ Bhp, const short* __restrict__ Blp,
    const float* __restrict__ cb, const float* __restrict__ pb,
    const float* __restrict__ bias,
    bf16* __restrict__ oq, bf16* __restrict__ oqp,
    bf16* __restrict__ ok, bf16* __restrict__ ov,
    float* __restrict__ ofp) {
  __shared__ short AsH[128][40];
  __shared__ short AsL[SPLITA ? 128 : 1][40];
  __shared__ short BsH[128][40];
  __shared__ short BsL[128][40];

  const int t = threadIdx.x, lane = t & 63, w = t >> 6;
  const int quad = lane >> 4, l15 = lane & 15;
  const int wm = (w >> 1) * 64, wn = (w & 1) * 64;
  const int m0 = blockIdx.x * 128, n0 = blockIdx.y * 128;

  const int sr = t >> 1;
  const int sc = (t & 1) * 16;

  f32x4 acc[4][4];
#pragma unroll
  for (int i = 0; i < 4; i++)
#pragma unroll
    for (int j = 0; j < 4; j++) acc[i][j] = (f32x4){0.f, 0.f, 0.f, 0.f};

  for (int k0 = 0; k0 < KDIM; k0 += 32) {
    __syncthreads();
    {
      const size_t ga = (size_t)(m0 + sr) * KDIM + k0 + sc;
      *(uint4*)&AsH[sr][sc]     = *(const uint4*)&Ah[ga];
      *(uint4*)&AsH[sr][sc + 8] = *(const uint4*)&Ah[ga + 8];
      if (SPLITA) {
        *(uint4*)&AsL[sr][sc]     = *(const uint4*)&Al[ga];
        *(uint4*)&AsL[sr][sc + 8] = *(const uint4*)&Al[ga + 8];
      }
      const size_t gb = (size_t)(n0 + sr) * KDIM + k0 + sc;
      *(uint4*)&BsH[sr][sc]     = *(const uint4*)&Bhp[gb];
      *(uint4*)&BsH[sr][sc + 8] = *(const uint4*)&Bhp[gb + 8];
      *(uint4*)&BsL[sr][sc]     = *(const uint4*)&Blp[gb];
      *(uint4*)&BsL[sr][sc + 8] = *(const uint4*)&Blp[gb + 8];
    }
    __syncthreads();

    short8 amh[4], aml[4], bnh[4], bnl[4];
#pragma unroll
    for (int i = 0; i < 4; i++) {
      amh[i] = *(const short8*)&AsH[wm + i * 16 + l15][quad * 8];
      if (SPLITA) aml[i] = *(const short8*)&AsL[wm + i * 16 + l15][quad * 8];
      bnh[i] = *(const short8*)&BsH[wn + i * 16 + l15][quad * 8];
      bnl[i] = *(const short8*)&BsL[wn + i * 16 + l15][quad * 8];
    }
#pragma unroll
    for (int i = 0; i < 4; i++) {
#pragma unroll
      for (int j = 0; j < 4; j++) {
        acc[i][j] = __builtin_amdgcn_mfma_f32_16x16x32_bf16(amh[i], bnh[j], acc[i][j], 0, 0, 0);
        acc[i][j] = __builtin_amdgcn_mfma_f32_16x16x32_bf16(amh[i], bnl[j], acc[i][j], 0, 0, 0);
        if (SPLITA)
          acc[i][j] = __builtin_amdgcn_mfma_f32_16x16x32_bf16(aml[i], bnh[j], acc[i][j], 0, 0, 0);
      }
    }
  }

  const int sel = (EPI == 0) ? (int)(blockIdx.y >> 2) : 0;
#pragma unroll
  for (int i = 0; i < 4; i++) {
#pragma unroll
    for (int j = 0; j < 4; j++) {
      const int n = n0 + wn + j * 16 + l15;
#pragma unroll
      for (int g = 0; g < 4; g++) {
        const int m = m0 + wm + i * 16 + quad * 4 + g;
        const float v = acc[i][j][g];
        if (EPI == 0) {
          const int hd_ = n & 511, hh = hd_ >> 6, d = hd_ & 63;
          const int b = m >> 11, s = m & 2047;
          const size_t idx = (((size_t)(b * HEADS + hh) * SEQ) + s) * DK + d;
          if (sel == 0) {
            const float sv = v * 0.125f;
            oq[idx]  = __float2bfloat16(sv + cb[hh * DK + d]);
            oqp[idx] = __float2bfloat16(sv + pb[hh * DK + d]);
          } else if (sel == 1) {
            ok[idx] = __float2bfloat16(v);
          } else {
            ov[idx] = __float2bfloat16(v);
          }
        } else if (EPI == 1) {
          const int hh = n >> 6, d = n & 63;
          if (m < NPOS) oq[((size_t)hh * NPOS + m) * DK + d] = __float2bfloat16(v);
        } else {
          ofp[(size_t)m * DIMM + n] = v + bias[n];
        }
      }
    }
  }
}

// ---------------- 4. no-max attention: LDS rel + LDS V^T staging ----------------
// grid (SEQ/64, BH, 2), block 256 = 4 waves; wave w owns q-rows [i0+16w, +16).
// exp(s-12) cancels in merge. l via ones-MFMA. bpermute rel-shift.
// K direct-from-global (R6-proven); rel + V^T cooperatively LDS-staged
// (vectorized b128 both ways); PV is pure ds_read+MFMA. No register-array
// prefetch (R9 spill lesson). LDS 36.9 KB -> 4 blocks/CU.
__global__ __launch_bounds__(256) void attn_mfma4(
    const short* __restrict__ qc, const short* __restrict__ qp,
    const short* __restrict__ kg, const short* __restrict__ vt,
    const short* __restrict__ relk,
    float* __restrict__ Op, float* __restrict__ Lp) {
  __shared__ short Rel_lds[128][72];     // block's rel window (128 rows)
  __shared__ short Vt_lds[64][72];       // V^T tile: [d][j]
  __shared__ short Pw[4][16][72];        // per-wave P in A-layout

  const int t    = threadIdx.x;
  const int lane = t & 63;
  const int w    = t >> 6;
  const int quad = lane >> 4;
  const int l15  = lane & 15;
  const int bh   = blockIdx.y;
  const int h    = bh & 7;
  const int i0   = blockIdx.x * 64;
  const int z    = blockIdx.z;
  const int jb   = z * (SEQ / 2);

  short8 qcA[2], qpA[2];
  {
    const size_t qrow = ((size_t)bh * SEQ + i0 + w * 16 + l15) * DK + quad * 8;
    qcA[0] = *(const short8*)(qc + qrow);
    qcA[1] = *(const short8*)(qc + qrow + 32);
    qpA[0] = *(const short8*)(qp + qrow);
    qpA[1] = *(const short8*)(qp + qrow + 32);
  }

  int idxg[4]; bool selg[4];
#pragma unroll
  for (int g = 0; g < 4; g++) {
    const int r = quad * 4 + g;
    idxg[g] = (((lane & 48) | ((l15 + 15 - r) & 15)) << 2);
    selg[g] = (l15 <= r);
  }

  short8 ones8;
#pragma unroll
  for (int e = 0; e < 8; e++) ones8[e] = (short)0x3F80;   // bf16 1.0

  f32x4 oacc[4];
#pragma unroll
  for (int dt = 0; dt < 4; dt++) oacc[dt] = (f32x4){0.f, 0.f, 0.f, 0.f};
  f32x4 lacc = (f32x4){0.f, 0.f, 0.f, 0.f};

  const short* kbase = kg + (size_t)bh * SEQ * DK;
  const short* vbase = vt + (size_t)bh * DK * SEQ;
  const short* rbase = relk + (size_t)h * NPOS * DK;

  const int rr  = t >> 1, rcc = (t & 1) * 32;   // rel staging: row rr, 32-short chunk
  const int vr  = t >> 2, vcc = (t & 3) * 16;   // V^T staging: row vr, 16-short chunk
  const int rb_w = 48 - 16 * w;                 // wave's window base in Rel_lds

  for (int jt = 0; jt < SEQ / 2 / 64; jt++) {
    const int j0 = jb + jt * 64;

    __syncthreads();
    // ---- stage rel rows p in [j0-i0+1984, +128) ----
    {
      const short* src = rbase + (size_t)((j0 - i0 + 1984) + rr) * DK + rcc;
      *(uint4*)&Rel_lds[rr][rcc]      = *(const uint4*)(src);
      *(uint4*)&Rel_lds[rr][rcc + 8]  = *(const uint4*)(src + 8);
      *(uint4*)&Rel_lds[rr][rcc + 16] = *(const uint4*)(src + 16);
      *(uint4*)&Rel_lds[rr][rcc + 24] = *(const uint4*)(src + 24);
    }
    // ---- stage V^T tile [64][64] (vectorized, pre-transposed source) ----
    {
      const short* src = vbase + (size_t)vr * SEQ + j0 + vcc;
      *(uint4*)&Vt_lds[vr][vcc]     = *(const uint4*)(src);
      *(uint4*)&Vt_lds[vr][vcc + 8] = *(const uint4*)(src + 8);
    }
    __syncthreads();

    // ---- content S = Qc . K^T (B-frags direct from global) ----
    f32x4 sacc[4];
#pragma unroll
    for (int nt = 0; nt < 4; nt++) {
      const short* kr = kbase + (size_t)(j0 + nt * 16 + l15) * DK + quad * 8;
      short8 b0 = *(const short8*)kr;
      short8 b1 = *(const short8*)(kr + 32);
      f32x4 a = (f32x4){0.f, 0.f, 0.f, 0.f};
      a = __builtin_amdgcn_mfma_f32_16x16x32_bf16(qcA[0], b0, a, 0, 0, 0);
      a = __builtin_amdgcn_mfma_f32_16x16x32_bf16(qcA[1], b1, a, 0, 0, 0);
      sacc[nt] = a;
    }

    // ---- rel logits (LDS B-frags) -> rolling bpermute shift -> exp -> Pw ----
    f32x4 rprev;
    {
      const short* rl = &Rel_lds[rb_w + l15][quad * 8];
      short8 b0 = *(const short8*)rl;
      short8 b1 = *(const short8*)(rl + 32);
      f32x4 a = (f32x4){0.f, 0.f, 0.f, 0.f};
      a = __builtin_amdgcn_mfma_f32_16x16x32_bf16(qpA[0], b0, a, 0, 0, 0);
      a = __builtin_amdgcn_mfma_f32_16x16x32_bf16(qpA[1], b1, a, 0, 0, 0);
      rprev = a;
    }
    f32x4 bpp;
#pragma unroll
    for (int g = 0; g < 4; g++)
      bpp[g] = __int_as_float(__builtin_amdgcn_ds_bpermute(idxg[g], __float_as_int(rprev[g])));

#pragma unroll
    for (int nt = 0; nt < 4; nt++) {
      f32x4 rcur;
      {
        const short* rl = &Rel_lds[rb_w + (nt + 1) * 16 + l15][quad * 8];
        short8 b0 = *(const short8*)rl;
        short8 b1 = *(const short8*)(rl + 32);
        f32x4 a = (f32x4){0.f, 0.f, 0.f, 0.f};
        a = __builtin_amdgcn_mfma_f32_16x16x32_bf16(qpA[0], b0, a, 0, 0, 0);
        a = __builtin_amdgcn_mfma_f32_16x16x32_bf16(qpA[1], b1, a, 0, 0, 0);
        rcur = a;
      }
      f32x4 bpc;
#pragma unroll
      for (int g = 0; g < 4; g++)
        bpc[g] = __int_as_float(__builtin_amdgcn_ds_bpermute(idxg[g], __float_as_int(rcur[g])));
#pragma unroll
      for (int g = 0; g < 4; g++) {
        const float relv = selg[g] ? bpp[g] : bpc[g];
        const float s = sacc[nt][g] + relv;
        const float p = __expf(s - 12.0f);
        Pw[w][quad * 4 + g][nt * 16 + l15] = (short)f2bf(p);
      }
      bpp = bpc;
    }

    // ---- PV + row-sum: all operands from LDS (compiler-pipelined lgkmcnt) ----
#pragma unroll
    for (int ks = 0; ks < 2; ks++) {
      short8 pA = *(const short8*)&Pw[w][l15][ks * 32 + quad * 8];
      lacc = __builtin_amdgcn_mfma_f32_16x16x32_bf16(pA, ones8, lacc, 0, 0, 0);
#pragma unroll
      for (int dt = 0; dt < 4; dt++) {
        short8 vB = *(const short8*)&Vt_lds[dt * 16 + l15][ks * 32 + quad * 8];
        oacc[dt] = __builtin_amdgcn_mfma_f32_16x16x32_bf16(pA, vB, oacc[dt], 0, 0, 0);
      }
    }
  }

  // ---- epilogue: store partial O (unnormalized) and l ----
  const size_t obase = ((size_t)(z * BH + bh) * SEQ + i0 + w * 16);
#pragma unroll
  for (int g = 0; g < 4; g++) {
    const int r = quad * 4 + g;
#pragma unroll
    for (int dt = 0; dt < 4; dt++)
      Op[(obase + r) * DK + dt * 16 + l15] = oacc[dt][g];
    if (l15 == 0) Lp[obase + r] = lacc[g];
  }
}

// ---------------- 5. merge halves -> oh bf16 ----------------
__global__ void merge_kernel(const float* __restrict__ Op, const float* __restrict__ Lp,
                             bf16* __restrict__ oh) {
  const int gid = blockIdx.x * 256 + threadIdx.x;
  const int m = gid >> 7;
  const int n0 = (gid & 127) * 4;
  const int b = m >> 11, s = m & 2047;
  const int hh = n0 >> 6, d0 = n0 & 63;
  const int bh = b * HEADS + hh;
  const float l = Lp[(size_t)bh * SEQ + s] + Lp[((size_t)BH + bh) * SEQ + s];
  const float inv = 1.0f / l;
  const float4 o0 = *(const float4*)&Op[((size_t)bh * SEQ + s) * DK + d0];
  const float4 o1 = *(const float4*)&Op[(((size_t)BH + bh) * SEQ + s) * DK + d0];
  *(uint2*)&oh[(size_t)m * HD + n0] = make_uint2(
      f2bf((o0.x + o1.x) * inv) | (f2bf((o0.y + o1.y) * inv) << 16),
      f2bf((o0.z + o1.z) * inv) | (f2bf((o0.w + o1.w) * inv) << 16));
}

// ---------------- launch ----------------
extern "C" void kernel_launch(void* const* d_in, const int* in_sizes, int n_in,
                              void* d_out, int out_size, void* d_ws, size_t ws_size,
                              hipStream_t stream) {
  (void)in_sizes; (void)n_in; (void)out_size; (void)ws_size;
  const float* x    = (const float*)d_in[0];
  const float* Wq   = (const float*)d_in[1];
  const float* Wk   = (const float*)d_in[2];
  const float* Wv   = (const float*)d_in[3];
  const float* Wrel = (const float*)d_in[4];
  const float* Wout = (const float*)d_in[5];
  const float* bout = (const float*)d_in[6];
  const float* cb   = (const float*)d_in[7];
  const float* pb   = (const float*)d_in[8];
  float* out = (float*)d_out;

  char* ws = (char*)d_ws;
  bf16*  relk = (bf16*)(ws + OB_RELK);
  bf16*  qc   = (bf16*)(ws + OB_QC);
  bf16*  qp   = (bf16*)(ws + OB_QP);
  bf16*  kk   = (bf16*)(ws + OB_K);
  bf16*  vv   = (bf16*)(ws + OB_V);
  bf16*  oh   = (bf16*)(ws + OB_OH);
  short* vt   = (short*)(ws + OB_VT);
  float* Opb  = (float*)(ws + OB_OP);
  float* Lpb  = (float*)(ws + OB_LP);
  short* embh = (short*)(ws + OB_EMBH);
  short* embl = (short*)(ws + OB_EMBL);
  short* xh   = (short*)(ws + OB_XH);
  short* xl   = (short*)(ws + OB_XL);
  short* wqh  = (short*)(ws + OB_WQKVH);
  short* wql  = (short*)(ws + OB_WQKVL);
  short* woh  = (short*)(ws + OB_WOH);
  short* wol  = (short*)(ws + OB_WOL);
  short* wrh  = (short*)(ws + OB_WRH);
  short* wrl  = (short*)(ws + OB_WRL);

  hipLaunchKernelGGL(pos_emb_kernel, dim3(2048), dim3(64), 0, stream, embh, embl);
  hipLaunchKernelGGL(conv_split, dim3(3072), dim3(256), 0, stream, x, xh, xl, ROWS * DIMM / 4);
  hipLaunchKernelGGL(transpose_split, dim3(16, 24), dim3(256), 0, stream, Wq,   wqh,                wql,                DIMM, HD);
  hipLaunchKernelGGL(transpose_split, dim3(16, 24), dim3(256), 0, stream, Wk,   wqh + 512 * DIMM,   wql + 512 * DIMM,   DIMM, HD);
  hipLaunchKernelGGL(transpose_split, dim3(16, 24), dim3(256), 0, stream, Wv,   wqh + 1024 * DIMM,  wql + 1024 * DIMM,  DIMM, HD);
  hipLaunchKernelGGL(transpose_split, dim3(24, 16), dim3(256), 0, stream, Wout, woh,                wol,                HD,   DIMM);
  hipLaunchKernelGGL(transpose_split, dim3(16, 6),  dim3(256), 0, stream, Wrel, wrh,                wrl,                192,  HD);

  hipLaunchKernelGGL((gemm128<1, 1, 192>), dim3(32, 4), dim3(256), 0, stream,
                     embh, embl, wrh, wrl, nullptr, nullptr, nullptr,
                     relk, nullptr, nullptr, nullptr, nullptr);
  hipLaunchKernelGGL((gemm128<0, 1, DIMM>), dim3(32, 12), dim3(256), 0, stream,
                     xh, xl, wqh, wql, cb, pb, nullptr,
                     qc, qp, kk, vv, nullptr);
  hipLaunchKernelGGL(vtrans_kernel, dim3(SEQ / 64, BH), dim3(256), 0, stream,
                     (const short*)vv, vt);
  hipLaunchKernelGGL(attn_mfma4, dim3(SEQ / 64, BH, 2), dim3(256), 0, stream,
                     (const short*)qc, (const short*)qp, (const short*)kk,
                     (const short*)vt, (const short*)relk, Opb, Lpb);
  hipLaunchKernelGGL(merge_kernel, dim3(ROWS * (HD / 4) / 256), dim3(256), 0, stream,
                     Opb, Lpb, oh);
  hipLaunchKernelGGL((gemm128<2, 0, HD>), dim3(32, 6), dim3(256), 0, stream,
                     (const short*)oh, nullptr, woh, wol, nullptr, nullptr, bout,
                     nullptr, nullptr, nullptr, nullptr, out);
}

// Round 11
// 248.323 us; speedup vs baseline: 1.8757x; 1.0921x over previous
//
#include <hip/hip_runtime.h>
#include <hip/hip_bf16.h>
#include <math.h>

typedef __hip_bfloat16 bf16;
typedef __attribute__((ext_vector_type(8))) short short8;  // 8 bf16 = 4 VGPRs
typedef __attribute__((ext_vector_type(4))) float f32x4;

#define SEQ   2048
#define NPOS  4095          // 2*SEQ-1
#define DIMM  768
#define HEADS 8
#define DK    64
#define HD    512           // HEADS*DK
#define BATCH 2
#define BH    16            // BATCH*HEADS
#define ROWS  4096          // BATCH*SEQ

// ---------------- workspace layout (BYTE offsets), ~44.4 MB ----------------
#define OB_RELK  ((size_t)0)                      // bf16 [8][4095][64] (+pad)
#define OB_QC    ((size_t)4194304)
#define OB_QP    ((size_t)8388608)
#define OB_K     ((size_t)12582912)
#define OB_V     ((size_t)16777216)
#define OB_OH    ((size_t)20971520)               // bf16 [4096][512]
// aliased (disjoint lifetimes):
#define OB_EMBH  OB_OH                            // dead after gemm_qr
#define OB_EMBL  ((size_t)(OB_OH + 1572864))
#define OB_VT    OB_OH                            // V^T, dead before merge writes oh
#define OB_XH    ((size_t)25165824)               // dead after gemm_qr
#define OB_XL    ((size_t)31457280)
#define OB_WQKVH ((size_t)37748736)               // dead after gemm_qr
#define OB_WQKVL ((size_t)40108032)
#define OB_OP    ((size_t)25165824)               // f32 [2][16][2048][64] partial O
#define OB_LP    ((size_t)41943040)               // f32 [2][16][2048] partial l
#define OB_WOH   ((size_t)42467328)               // out-proj weights
#define OB_WOL   ((size_t)43253760)
#define OB_WRH   ((size_t)44040192)
#define OB_WRL   ((size_t)44236800)

// RNE float -> bf16 bits (finite inputs only)
__device__ __forceinline__ unsigned f2bf(float f) {
  unsigned u = __float_as_uint(f);
  return (u + 0x7fffu + ((u >> 16) & 1u)) >> 16;
}
__device__ __forceinline__ void split2(float v, unsigned& hb, unsigned& lb) {
  hb = f2bf(v);
  const float back = __uint_as_float(hb << 16);
  lb = f2bf(v - back);
}

// ---------------- 1. fused prep: pos_emb + conv_split + 5 transposes ----------------
// grid 5216 x 256:
//   [0,512):     pos_emb, 8 rows/block
//   [512,3584):  conv_split of x (786432 float4s)
//   [3584,5216): transpose_split of Wq/Wk/Wv/Wout/Wrel
__global__ __launch_bounds__(256) void prep_all(
    const float* __restrict__ x,
    const float* __restrict__ Wq, const float* __restrict__ Wk,
    const float* __restrict__ Wv, const float* __restrict__ Wout,
    const float* __restrict__ Wrel,
    short* __restrict__ eh, short* __restrict__ el,
    short* __restrict__ xh, short* __restrict__ xl,
    short* __restrict__ wqkvh, short* __restrict__ wqkvl,
    short* __restrict__ woh, short* __restrict__ wol,
    short* __restrict__ wrh, short* __restrict__ wrl) {
  __shared__ float tile[32][33];
  const int blk = blockIdx.x;
  const int t = threadIdx.x;

  if (blk < 512) {
    // ---- positional embedding -> split bf16 ----
    const int row = blk * 8 + (t >> 5);
    const int j   = t & 31;
    if (row >= NPOS) {         // row 4095 pad: zero so relk GEMM A-frag is clean
      for (int c = j; c < 192; c += 32) { eh[(size_t)row * 192 + c] = 0; el[(size_t)row * 192 + c] = 0; }
      return;
    }
    const float dist = (float)(row - (SEQ - 1));
    const float ad   = fabsf(dist);
    const float hl    = exp2f(3.0f + 8.0f * (float)j / 31.0f);
    const float f_exp = exp2f(-ad / hl);
    const float width = exp2f((float)(j + 1)) - 1.0f;
    const float f_cm  = (width > ad) ? 1.0f : 0.0f;
    float prob;
    if (ad > 0.0f) {
      const float c   = 4.0f * (float)((j + 1) * (j + 1));
      const float r   = (float)(j + 1) / 16.0f;
      const float lu  = (c - 1.0f) * logf(ad) - r * ad;
      const float ln_ = lgammaf(c) - c * logf(r);
      prob = expf(lu - ln_) + 1e-8f;
    } else {
      prob = 1e-8f;
    }
    float mx = prob;
    for (int off = 16; off; off >>= 1) mx = fmaxf(mx, __shfl_xor(mx, off, 32));
    const float f_g = prob / mx;
    const float s = (dist > 0.f) ? 1.f : ((dist < 0.f) ? -1.f : 0.f);
    const float vals[6] = {f_exp, f_cm, f_g, s * f_exp, s * f_cm, s * f_g};
    short* ph = eh + (size_t)row * 192;
    short* pl = el + (size_t)row * 192;
#pragma unroll
    for (int q = 0; q < 6; q++) {
      unsigned hb, lb;
      split2(vals[q], hb, lb);
      ph[q * 32 + j] = (short)hb;
      pl[q * 32 + j] = (short)lb;
    }
    return;
  }

  if (blk < 3584) {
    // ---- x fp32 -> split bf16 (float4 granules) ----
    const int i = (blk - 512) * 256 + t;          // < 786432 exactly
    const float4 v = ((const float4*)x)[i];
    unsigned h0, l0, h1, l1, h2, l2, h3, l3;
    split2(v.x, h0, l0); split2(v.y, h1, l1); split2(v.z, h2, l2); split2(v.w, h3, l3);
    *(uint2*)&xh[(size_t)i * 4] = make_uint2(h0 | (h1 << 16), h2 | (h3 << 16));
    *(uint2*)&xl[(size_t)i * 4] = make_uint2(l0 | (l1 << 16), l2 | (l3 << 16));
    return;
  }

  // ---- weight transposes fp32 [R][C] -> split bf16 [C][R] ----
  const float* src; short* dh; short* dl; int R, C, local;
  if (blk < 3968)      { local = blk - 3584; src = Wq;   dh = wqkvh;               dl = wqkvl;               R = DIMM; C = HD; }
  else if (blk < 4352) { local = blk - 3968; src = Wk;   dh = wqkvh + 512 * DIMM;  dl = wqkvl + 512 * DIMM;  R = DIMM; C = HD; }
  else if (blk < 4736) { local = blk - 4352; src = Wv;   dh = wqkvh + 1024 * DIMM; dl = wqkvl + 1024 * DIMM; R = DIMM; C = HD; }
  else if (blk < 5120) { local = blk - 4736; src = Wout; dh = woh;  dl = wol;  R = HD;  C = DIMM; }
  else                 { local = blk - 5120; src = Wrel; dh = wrh;  dl = wrl;  R = 192; C = HD; }
  const int ctiles = C / 32;
  const int c0 = (local % ctiles) * 32, r0 = (local / ctiles) * 32;
  {
    const int lr = t >> 3, lc = (t & 7) * 4;
    const float4 v = *(const float4*)&src[(size_t)(r0 + lr) * C + c0 + lc];
    tile[lr][lc] = v.x; tile[lr][lc + 1] = v.y; tile[lr][lc + 2] = v.z; tile[lr][lc + 3] = v.w;
  }
  __syncthreads();
  const int nn = t >> 3, kb = (t & 7) * 4;
  unsigned hb[4], lb[4];
#pragma unroll
  for (int e = 0; e < 4; e++) split2(tile[kb + e][nn], hb[e], lb[e]);
  const size_t o = (size_t)(c0 + nn) * R + r0 + kb;
  *(uint2*)&dh[o] = make_uint2(hb[0] | (hb[1] << 16), hb[2] | (hb[3] << 16));
  *(uint2*)&dl[o] = make_uint2(lb[0] | (lb[1] << 16), lb[2] | (lb[3] << 16));
}

// ---------------- 2. V transpose: vv [bh][s][64] -> vt [bh][64][2048] ----------------
__global__ void vtrans_kernel(const short* __restrict__ vv, short* __restrict__ vt) {
  __shared__ short tile[64][72];
  const int t = threadIdx.x;
  const int s0 = blockIdx.x * 64, bh = blockIdx.y;
  {
    const int sl = t >> 2, dc = (t & 3) * 16;
    const short* src = vv + ((size_t)bh * SEQ + s0 + sl) * DK + dc;
    *(uint4*)&tile[sl][dc]     = *(const uint4*)src;
    *(uint4*)&tile[sl][dc + 8] = *(const uint4*)(src + 8);
  }
  __syncthreads();
  const int dr = t >> 6, sc = t & 63;
#pragma unroll
  for (int it = 0; it < 16; it++) {
    const int d = it * 4 + dr;
    vt[((size_t)bh * DK + d) * SEQ + s0 + sc] = tile[sc][d];
  }
}

// ---------------- 3. unified qkv+relk split-bf16 MFMA GEMM ----------------
// grid 512 x 256: blocks [0,384) = qkv tiles (M=4096,N=1536,K=768);
// blocks [384,512) = relk tiles (M=4096,N=512,K=192). 128x128 tile, BK=32.
__global__ __launch_bounds__(256) void gemm_qr(
    const short* __restrict__ xh, const short* __restrict__ xl,
    const short* __restrict__ wqkvh, const short* __restrict__ wqkvl,
    const short* __restrict__ eh, const short* __restrict__ el,
    const short* __restrict__ wrh, const short* __restrict__ wrl,
    const float* __restrict__ cb, const float* __restrict__ pb,
    bf16* __restrict__ oq, bf16* __restrict__ oqp,
    bf16* __restrict__ ok, bf16* __restrict__ ov,
    bf16* __restrict__ relk) {
  __shared__ short AsH[128][40];
  __shared__ short AsL[128][40];
  __shared__ short BsH[128][40];
  __shared__ short BsL[128][40];

  const int bx = blockIdx.x;
  const bool isq = bx < 384;
  const int lbx = isq ? bx : bx - 384;
  const int mt = lbx & 31, ntile = lbx >> 5;
  const int m0 = mt * 128, n0 = ntile * 128;
  const int KD = isq ? DIMM : 192;
  const short* Ah = isq ? xh : eh;
  const short* Al = isq ? xl : el;
  const short* Bh = isq ? wqkvh : wrh;
  const short* Bl = isq ? wqkvl : wrl;

  const int t = threadIdx.x, lane = t & 63, w = t >> 6;
  const int quad = lane >> 4, l15 = lane & 15;
  const int wm = (w >> 1) * 64, wn = (w & 1) * 64;
  const int sr = t >> 1;
  const int sc = (t & 1) * 16;

  f32x4 acc[4][4];
#pragma unroll
  for (int i = 0; i < 4; i++)
#pragma unroll
    for (int j = 0; j < 4; j++) acc[i][j] = (f32x4){0.f, 0.f, 0.f, 0.f};

  for (int k0 = 0; k0 < KD; k0 += 32) {
    __syncthreads();
    {
      const size_t ga = (size_t)(m0 + sr) * KD + k0 + sc;
      *(uint4*)&AsH[sr][sc]     = *(const uint4*)&Ah[ga];
      *(uint4*)&AsH[sr][sc + 8] = *(const uint4*)&Ah[ga + 8];
      *(uint4*)&AsL[sr][sc]     = *(const uint4*)&Al[ga];
      *(uint4*)&AsL[sr][sc + 8] = *(const uint4*)&Al[ga + 8];
      const size_t gb = (size_t)(n0 + sr) * KD + k0 + sc;
      *(uint4*)&BsH[sr][sc]     = *(const uint4*)&Bh[gb];
      *(uint4*)&BsH[sr][sc + 8] = *(const uint4*)&Bh[gb + 8];
      *(uint4*)&BsL[sr][sc]     = *(const uint4*)&Bl[gb];
      *(uint4*)&BsL[sr][sc + 8] = *(const uint4*)&Bl[gb + 8];
    }
    __syncthreads();

    short8 amh[4], aml[4], bnh[4], bnl[4];
#pragma unroll
    for (int i = 0; i < 4; i++) {
      amh[i] = *(const short8*)&AsH[wm + i * 16 + l15][quad * 8];
      aml[i] = *(const short8*)&AsL[wm + i * 16 + l15][quad * 8];
      bnh[i] = *(const short8*)&BsH[wn + i * 16 + l15][quad * 8];
      bnl[i] = *(const short8*)&BsL[wn + i * 16 + l15][quad * 8];
    }
#pragma unroll
    for (int i = 0; i < 4; i++) {
#pragma unroll
      for (int j = 0; j < 4; j++) {
        acc[i][j] = __builtin_amdgcn_mfma_f32_16x16x32_bf16(amh[i], bnh[j], acc[i][j], 0, 0, 0);
        acc[i][j] = __builtin_amdgcn_mfma_f32_16x16x32_bf16(amh[i], bnl[j], acc[i][j], 0, 0, 0);
        acc[i][j] = __builtin_amdgcn_mfma_f32_16x16x32_bf16(aml[i], bnh[j], acc[i][j], 0, 0, 0);
      }
    }
  }

  if (isq) {
    const int sel = ntile >> 2;   // 0=q,1=k,2=v
#pragma unroll
    for (int i = 0; i < 4; i++) {
#pragma unroll
      for (int j = 0; j < 4; j++) {
        const int n = n0 + wn + j * 16 + l15;
        const int hd_ = n & 511, hh = hd_ >> 6, d = hd_ & 63;
#pragma unroll
        for (int g = 0; g < 4; g++) {
          const int m = m0 + wm + i * 16 + quad * 4 + g;
          const int b = m >> 11, s = m & 2047;
          const size_t idx = (((size_t)(b * HEADS + hh) * SEQ) + s) * DK + d;
          const float v = acc[i][j][g];
          if (sel == 0) {
            const float sv = v * 0.125f;   // dk^-0.5
            oq[idx]  = __float2bfloat16(sv + cb[hh * DK + d]);
            oqp[idx] = __float2bfloat16(sv + pb[hh * DK + d]);
          } else if (sel == 1) {
            ok[idx] = __float2bfloat16(v);
          } else {
            ov[idx] = __float2bfloat16(v);
          }
        }
      }
    }
  } else {
#pragma unroll
    for (int i = 0; i < 4; i++) {
#pragma unroll
      for (int j = 0; j < 4; j++) {
        const int n = n0 + wn + j * 16 + l15;
        const int hh = n >> 6, d = n & 63;
#pragma unroll
        for (int g = 0; g < 4; g++) {
          const int m = m0 + wm + i * 16 + quad * 4 + g;
          if (m < NPOS) relk[((size_t)hh * NPOS + m) * DK + d] = __float2bfloat16(acc[i][j][g]);
        }
      }
    }
  }
}

// ---------------- 4. out-projection GEMM (bf16 A x split-bf16 W) ----------------
__global__ __launch_bounds__(256) void out_gemm(
    const short* __restrict__ Ahp,
    const short* __restrict__ Bhp, const short* __restrict__ Blp,
    const float* __restrict__ bias, float* __restrict__ ofp) {
  __shared__ short AsH[128][40];
  __shared__ short BsH[128][40];
  __shared__ short BsL[128][40];

  const int t = threadIdx.x, lane = t & 63, w = t >> 6;
  const int quad = lane >> 4, l15 = lane & 15;
  const int wm = (w >> 1) * 64, wn = (w & 1) * 64;
  const int m0 = blockIdx.x * 128, n0 = blockIdx.y * 128;
  const int sr = t >> 1;
  const int sc = (t & 1) * 16;

  f32x4 acc[4][4];
#pragma unroll
  for (int i = 0; i < 4; i++)
#pragma unroll
    for (int j = 0; j < 4; j++) acc[i][j] = (f32x4){0.f, 0.f, 0.f, 0.f};

  for (int k0 = 0; k0 < HD; k0 += 32) {
    __syncthreads();
    {
      const size_t ga = (size_t)(m0 + sr) * HD + k0 + sc;
      *(uint4*)&AsH[sr][sc]     = *(const uint4*)&Ahp[ga];
      *(uint4*)&AsH[sr][sc + 8] = *(const uint4*)&Ahp[ga + 8];
      const size_t gb = (size_t)(n0 + sr) * HD + k0 + sc;
      *(uint4*)&BsH[sr][sc]     = *(const uint4*)&Bhp[gb];
      *(uint4*)&BsH[sr][sc + 8] = *(const uint4*)&Bhp[gb + 8];
      *(uint4*)&BsL[sr][sc]     = *(const uint4*)&Blp[gb];
      *(uint4*)&BsL[sr][sc + 8] = *(const uint4*)&Blp[gb + 8];
    }
    __syncthreads();

    short8 amh[4], bnh[4], bnl[4];
#pragma unroll
    for (int i = 0; i < 4; i++) {
      amh[i] = *(const short8*)&AsH[wm + i * 16 + l15][quad * 8];
      bnh[i] = *(const short8*)&BsH[wn + i * 16 + l15][quad * 8];
      bnl[i] = *(const short8*)&BsL[wn + i * 16 + l15][quad * 8];
    }
#pragma unroll
    for (int i = 0; i < 4; i++) {
#pragma unroll
      for (int j = 0; j < 4; j++) {
        acc[i][j] = __builtin_amdgcn_mfma_f32_16x16x32_bf16(amh[i], bnh[j], acc[i][j], 0, 0, 0);
        acc[i][j] = __builtin_amdgcn_mfma_f32_16x16x32_bf16(amh[i], bnl[j], acc[i][j], 0, 0, 0);
      }
    }
  }

#pragma unroll
  for (int i = 0; i < 4; i++) {
#pragma unroll
    for (int j = 0; j < 4; j++) {
      const int n = n0 + wn + j * 16 + l15;
      const float bv = bias[n];
#pragma unroll
      for (int g = 0; g < 4; g++) {
        const int m = m0 + wm + i * 16 + quad * 4 + g;
        ofp[(size_t)m * DIMM + n] = acc[i][j][g] + bv;
      }
    }
  }
}

// ---------------- 5. no-max attention: LDS rel + LDS V^T staging ----------------
__global__ __launch_bounds__(256) void attn_mfma4(
    const short* __restrict__ qc, const short* __restrict__ qp,
    const short* __restrict__ kg, const short* __restrict__ vt,
    const short* __restrict__ relk,
    float* __restrict__ Op, float* __restrict__ Lp) {
  __shared__ short Rel_lds[128][72];     // block's rel window (128 rows)
  __shared__ short Vt_lds[64][72];       // V^T tile: [d][j]
  __shared__ short Pw[4][16][72];        // per-wave P in A-layout

  const int t    = threadIdx.x;
  const int lane = t & 63;
  const int w    = t >> 6;
  const int quad = lane >> 4;
  const int l15  = lane & 15;
  const int bh   = blockIdx.y;
  const int h    = bh & 7;
  const int i0   = blockIdx.x * 64;
  const int z    = blockIdx.z;
  const int jb   = z * (SEQ / 2);

  short8 qcA[2], qpA[2];
  {
    const size_t qrow = ((size_t)bh * SEQ + i0 + w * 16 + l15) * DK + quad * 8;
    qcA[0] = *(const short8*)(qc + qrow);
    qcA[1] = *(const short8*)(qc + qrow + 32);
    qpA[0] = *(const short8*)(qp + qrow);
    qpA[1] = *(const short8*)(qp + qrow + 32);
  }

  int idxg[4]; bool selg[4];
#pragma unroll
  for (int g = 0; g < 4; g++) {
    const int r = quad * 4 + g;
    idxg[g] = (((lane & 48) | ((l15 + 15 - r) & 15)) << 2);
    selg[g] = (l15 <= r);
  }

  short8 ones8;
#pragma unroll
  for (int e = 0; e < 8; e++) ones8[e] = (short)0x3F80;   // bf16 1.0

  f32x4 oacc[4];
#pragma unroll
  for (int dt = 0; dt < 4; dt++) oacc[dt] = (f32x4){0.f, 0.f, 0.f, 0.f};
  f32x4 lacc = (f32x4){0.f, 0.f, 0.f, 0.f};

  const short* kbase = kg + (size_t)bh * SEQ * DK;
  const short* vbase = vt + (size_t)bh * DK * SEQ;
  const short* rbase = relk + (size_t)h * NPOS * DK;

  const int rr  = t >> 1, rcc = (t & 1) * 32;   // rel staging assignment
  const int vr  = t >> 2, vcc = (t & 3) * 16;   // V^T staging assignment
  const int rb_w = 48 - 16 * w;                 // wave's window base in Rel_lds

  for (int jt = 0; jt < SEQ / 2 / 64; jt++) {
    const int j0 = jb + jt * 64;

    __syncthreads();
    {
      const short* src = rbase + (size_t)((j0 - i0 + 1984) + rr) * DK + rcc;
      *(uint4*)&Rel_lds[rr][rcc]      = *(const uint4*)(src);
      *(uint4*)&Rel_lds[rr][rcc + 8]  = *(const uint4*)(src + 8);
      *(uint4*)&Rel_lds[rr][rcc + 16] = *(const uint4*)(src + 16);
      *(uint4*)&Rel_lds[rr][rcc + 24] = *(const uint4*)(src + 24);
    }
    {
      const short* src = vbase + (size_t)vr * SEQ + j0 + vcc;
      *(uint4*)&Vt_lds[vr][vcc]     = *(const uint4*)(src);
      *(uint4*)&Vt_lds[vr][vcc + 8] = *(const uint4*)(src + 8);
    }
    __syncthreads();

    // ---- content S = Qc . K^T (B-frags direct from global) ----
    f32x4 sacc[4];
#pragma unroll
    for (int nt = 0; nt < 4; nt++) {
      const short* kr = kbase + (size_t)(j0 + nt * 16 + l15) * DK + quad * 8;
      short8 b0 = *(const short8*)kr;
      short8 b1 = *(const short8*)(kr + 32);
      f32x4 a = (f32x4){0.f, 0.f, 0.f, 0.f};
      a = __builtin_amdgcn_mfma_f32_16x16x32_bf16(qcA[0], b0, a, 0, 0, 0);
      a = __builtin_amdgcn_mfma_f32_16x16x32_bf16(qcA[1], b1, a, 0, 0, 0);
      sacc[nt] = a;
    }

    // ---- rel logits (LDS B-frags) -> rolling bpermute shift -> exp -> Pw ----
    f32x4 rprev;
    {
      const short* rl = &Rel_lds[rb_w + l15][quad * 8];
      short8 b0 = *(const short8*)rl;
      short8 b1 = *(const short8*)(rl + 32);
      f32x4 a = (f32x4){0.f, 0.f, 0.f, 0.f};
      a = __builtin_amdgcn_mfma_f32_16x16x32_bf16(qpA[0], b0, a, 0, 0, 0);
      a = __builtin_amdgcn_mfma_f32_16x16x32_bf16(qpA[1], b1, a, 0, 0, 0);
      rprev = a;
    }
    f32x4 bpp;
#pragma unroll
    for (int g = 0; g < 4; g++)
      bpp[g] = __int_as_float(__builtin_amdgcn_ds_bpermute(idxg[g], __float_as_int(rprev[g])));

#pragma unroll
    for (int nt = 0; nt < 4; nt++) {
      f32x4 rcur;
      {
        const short* rl = &Rel_lds[rb_w + (nt + 1) * 16 + l15][quad * 8];
        short8 b0 = *(const short8*)rl;
        short8 b1 = *(const short8*)(rl + 32);
        f32x4 a = (f32x4){0.f, 0.f, 0.f, 0.f};
        a = __builtin_amdgcn_mfma_f32_16x16x32_bf16(qpA[0], b0, a, 0, 0, 0);
        a = __builtin_amdgcn_mfma_f32_16x16x32_bf16(qpA[1], b1, a, 0, 0, 0);
        rcur = a;
      }
      f32x4 bpc;
#pragma unroll
      for (int g = 0; g < 4; g++)
        bpc[g] = __int_as_float(__builtin_amdgcn_ds_bpermute(idxg[g], __float_as_int(rcur[g])));
#pragma unroll
      for (int g = 0; g < 4; g++) {
        const float relv = selg[g] ? bpp[g] : bpc[g];
        const float s = sacc[nt][g] + relv;
        const float p = __expf(s - 12.0f);
        Pw[w][quad * 4 + g][nt * 16 + l15] = (short)f2bf(p);
      }
      bpp = bpc;
    }

    // ---- PV + row-sum: all operands from LDS ----
#pragma unroll
    for (int ks = 0; ks < 2; ks++) {
      short8 pA = *(const short8*)&Pw[w][l15][ks * 32 + quad * 8];
      lacc = __builtin_amdgcn_mfma_f32_16x16x32_bf16(pA, ones8, lacc, 0, 0, 0);
#pragma unroll
      for (int dt = 0; dt < 4; dt++) {
        short8 vB = *(const short8*)&Vt_lds[dt * 16 + l15][ks * 32 + quad * 8];
        oacc[dt] = __builtin_amdgcn_mfma_f32_16x16x32_bf16(pA, vB, oacc[dt], 0, 0, 0);
      }
    }
  }

  const size_t obase = ((size_t)(z * BH + bh) * SEQ + i0 + w * 16);
#pragma unroll
  for (int g = 0; g < 4; g++) {
    const int r = quad * 4 + g;
#pragma unroll
    for (int dt = 0; dt < 4; dt++)
      Op[(obase + r) * DK + dt * 16 + l15] = oacc[dt][g];
    if (l15 == 0) Lp[obase + r] = lacc[g];
  }
}

// ---------------- 6. merge halves -> oh bf16 ----------------
__global__ void merge_kernel(const float* __restrict__ Op, const float* __restrict__ Lp,
                             bf16* __restrict__ oh) {
  const int gid = blockIdx.x * 256 + threadIdx.x;
  const int m = gid >> 7;
  const int n0 = (gid & 127) * 4;
  const int b = m >> 11, s = m & 2047;
  const int hh = n0 >> 6, d0 = n0 & 63;
  const int bh = b * HEADS + hh;
  const float l = Lp[(size_t)bh * SEQ + s] + Lp[((size_t)BH + bh) * SEQ + s];
  const float inv = 1.0f / l;
  const float4 o0 = *(const float4*)&Op[((size_t)bh * SEQ + s) * DK + d0];
  const float4 o1 = *(const float4*)&Op[(((size_t)BH + bh) * SEQ + s) * DK + d0];
  *(uint2*)&oh[(size_t)m * HD + n0] = make_uint2(
      f2bf((o0.x + o1.x) * inv) | (f2bf((o0.y + o1.y) * inv) << 16),
      f2bf((o0.z + o1.z) * inv) | (f2bf((o0.w + o1.w) * inv) << 16));
}

// ---------------- launch ----------------
extern "C" void kernel_launch(void* const* d_in, const int* in_sizes, int n_in,
                              void* d_out, int out_size, void* d_ws, size_t ws_size,
                              hipStream_t stream) {
  (void)in_sizes; (void)n_in; (void)out_size; (void)ws_size;
  const float* x    = (const float*)d_in[0];
  const float* Wq   = (const float*)d_in[1];
  const float* Wk   = (const float*)d_in[2];
  const float* Wv   = (const float*)d_in[3];
  const float* Wrel = (const float*)d_in[4];
  const float* Wout = (const float*)d_in[5];
  const float* bout = (const float*)d_in[6];
  const float* cb   = (const float*)d_in[7];
  const float* pb   = (const float*)d_in[8];
  float* out = (float*)d_out;

  char* ws = (char*)d_ws;
  bf16*  relk = (bf16*)(ws + OB_RELK);
  bf16*  qc   = (bf16*)(ws + OB_QC);
  bf16*  qp   = (bf16*)(ws + OB_QP);
  bf16*  kk   = (bf16*)(ws + OB_K);
  bf16*  vv   = (bf16*)(ws + OB_V);
  bf16*  oh   = (bf16*)(ws + OB_OH);
  short* vt   = (short*)(ws + OB_VT);
  float* Opb  = (float*)(ws + OB_OP);
  float* Lpb  = (float*)(ws + OB_LP);
  short* embh = (short*)(ws + OB_EMBH);
  short* embl = (short*)(ws + OB_EMBL);
  short* xh   = (short*)(ws + OB_XH);
  short* xl   = (short*)(ws + OB_XL);
  short* wqh  = (short*)(ws + OB_WQKVH);
  short* wql  = (short*)(ws + OB_WQKVL);
  short* woh  = (short*)(ws + OB_WOH);
  short* wol  = (short*)(ws + OB_WOL);
  short* wrh  = (short*)(ws + OB_WRH);
  short* wrl  = (short*)(ws + OB_WRL);

  hipLaunchKernelGGL(prep_all, dim3(5216), dim3(256), 0, stream,
                     x, Wq, Wk, Wv, Wout, Wrel,
                     embh, embl, xh, xl, wqh, wql, woh, wol, wrh, wrl);
  hipLaunchKernelGGL(gemm_qr, dim3(512), dim3(256), 0, stream,
                     xh, xl, wqh, wql, embh, embl, wrh, wrl,
                     cb, pb, qc, qp, kk, vv, relk);
  hipLaunchKernelGGL(vtrans_kernel, dim3(SEQ / 64, BH), dim3(256), 0, stream,
                     (const short*)vv, vt);
  hipLaunchKernelGGL(attn_mfma4, dim3(SEQ / 64, BH, 2), dim3(256), 0, stream,
                     (const short*)qc, (const short*)qp, (const short*)kk,
                     (const short*)vt, (const short*)relk, Opb, Lpb);
  hipLaunchKernelGGL(merge_kernel, dim3(ROWS * (HD / 4) / 256), dim3(256), 0, stream,
                     Opb, Lpb, oh);
  hipLaunchKernelGGL(out_gemm, dim3(32, 6), dim3(256), 0, stream,
                     (const short*)oh, woh, wol, bout, out);
}

// Round 12
// 245.048 us; speedup vs baseline: 1.9008x; 1.0134x over previous
//
#include <hip/hip_runtime.h>
#include <hip/hip_bf16.h>
#include <math.h>
#include <stdint.h>

typedef __hip_bfloat16 bf16;
typedef __attribute__((ext_vector_type(8))) short short8;  // 8 bf16 = 4 VGPRs
typedef __attribute__((ext_vector_type(4))) float f32x4;

#define SEQ   2048
#define NPOS  4095          // 2*SEQ-1
#define DIMM  768
#define HEADS 8
#define DK    64
#define HD    512           // HEADS*DK
#define BATCH 2
#define BH    16            // BATCH*HEADS
#define ROWS  4096          // BATCH*SEQ

// ---------------- workspace layout (BYTE offsets), ~44.4 MB ----------------
#define OB_RELK  ((size_t)0)                      // bf16 [8][4095][64] (+pad)
#define OB_QC    ((size_t)4194304)
#define OB_QP    ((size_t)8388608)
#define OB_K     ((size_t)12582912)
#define OB_V     ((size_t)16777216)
#define OB_OH    ((size_t)20971520)               // bf16 [4096][512]
// aliased (disjoint lifetimes):
#define OB_EMBH  OB_OH                            // dead after gemm_qr
#define OB_EMBL  ((size_t)(OB_OH + 1572864))
#define OB_VT    OB_OH                            // V^T, dead before merge writes oh
#define OB_XH    ((size_t)25165824)               // dead after gemm_qr
#define OB_XL    ((size_t)31457280)
#define OB_WQKVH ((size_t)37748736)               // dead after gemm_qr
#define OB_WQKVL ((size_t)40108032)
#define OB_OP    ((size_t)25165824)               // f32 [2][16][2048][64] partial O
#define OB_LP    ((size_t)41943040)               // f32 [2][16][2048] partial l
#define OB_WOH   ((size_t)42467328)               // out-proj weights
#define OB_WOL   ((size_t)43253760)
#define OB_WRH   ((size_t)44040192)
#define OB_WRL   ((size_t)44236800)

// RNE float -> bf16 bits (finite inputs only)
__device__ __forceinline__ unsigned f2bf(float f) {
  unsigned u = __float_as_uint(f);
  return (u + 0x7fffu + ((u >> 16) & 1u)) >> 16;
}
__device__ __forceinline__ void split2(float v, unsigned& hb, unsigned& lb) {
  hb = f2bf(v);
  const float back = __uint_as_float(hb << 16);
  lb = f2bf(v - back);
}

// async global->LDS 16B copy (m97 pattern; CK-style addrspace casts).
// l must be wave-uniform; HW writes l + lane*16. g is per-lane.
__device__ __forceinline__ void cp16(const short* g, short* l) {
  __builtin_amdgcn_global_load_lds(
      (__attribute__((address_space(1))) void*)(uintptr_t)(g),
      (__attribute__((address_space(3))) void*)(uint32_t)(uintptr_t)(l),
      16, 0, 0);
}

// ---------------- 1. fused prep: pos_emb + conv_split + 5 transposes ----------------
__global__ __launch_bounds__(256) void prep_all(
    const float* __restrict__ x,
    const float* __restrict__ Wq, const float* __restrict__ Wk,
    const float* __restrict__ Wv, const float* __restrict__ Wout,
    const float* __restrict__ Wrel,
    short* __restrict__ eh, short* __restrict__ el,
    short* __restrict__ xh, short* __restrict__ xl,
    short* __restrict__ wqkvh, short* __restrict__ wqkvl,
    short* __restrict__ woh, short* __restrict__ wol,
    short* __restrict__ wrh, short* __restrict__ wrl) {
  __shared__ float tile[32][33];
  const int blk = blockIdx.x;
  const int t = threadIdx.x;

  if (blk < 512) {
    const int row = blk * 8 + (t >> 5);
    const int j   = t & 31;
    if (row >= NPOS) {
      for (int c = j; c < 192; c += 32) { eh[(size_t)row * 192 + c] = 0; el[(size_t)row * 192 + c] = 0; }
      return;
    }
    const float dist = (float)(row - (SEQ - 1));
    const float ad   = fabsf(dist);
    const float hl    = exp2f(3.0f + 8.0f * (float)j / 31.0f);
    const float f_exp = exp2f(-ad / hl);
    const float width = exp2f((float)(j + 1)) - 1.0f;
    const float f_cm  = (width > ad) ? 1.0f : 0.0f;
    float prob;
    if (ad > 0.0f) {
      const float c   = 4.0f * (float)((j + 1) * (j + 1));
      const float r   = (float)(j + 1) / 16.0f;
      const float lu  = (c - 1.0f) * logf(ad) - r * ad;
      const float ln_ = lgammaf(c) - c * logf(r);
      prob = expf(lu - ln_) + 1e-8f;
    } else {
      prob = 1e-8f;
    }
    float mx = prob;
    for (int off = 16; off; off >>= 1) mx = fmaxf(mx, __shfl_xor(mx, off, 32));
    const float f_g = prob / mx;
    const float s = (dist > 0.f) ? 1.f : ((dist < 0.f) ? -1.f : 0.f);
    const float vals[6] = {f_exp, f_cm, f_g, s * f_exp, s * f_cm, s * f_g};
    short* ph = eh + (size_t)row * 192;
    short* pl = el + (size_t)row * 192;
#pragma unroll
    for (int q = 0; q < 6; q++) {
      unsigned hb, lb;
      split2(vals[q], hb, lb);
      ph[q * 32 + j] = (short)hb;
      pl[q * 32 + j] = (short)lb;
    }
    return;
  }

  if (blk < 3584) {
    const int i = (blk - 512) * 256 + t;
    const float4 v = ((const float4*)x)[i];
    unsigned h0, l0, h1, l1, h2, l2, h3, l3;
    split2(v.x, h0, l0); split2(v.y, h1, l1); split2(v.z, h2, l2); split2(v.w, h3, l3);
    *(uint2*)&xh[(size_t)i * 4] = make_uint2(h0 | (h1 << 16), h2 | (h3 << 16));
    *(uint2*)&xl[(size_t)i * 4] = make_uint2(l0 | (l1 << 16), l2 | (l3 << 16));
    return;
  }

  const float* src; short* dh; short* dl; int R, C, local;
  if (blk < 3968)      { local = blk - 3584; src = Wq;   dh = wqkvh;               dl = wqkvl;               R = DIMM; C = HD; }
  else if (blk < 4352) { local = blk - 3968; src = Wk;   dh = wqkvh + 512 * DIMM;  dl = wqkvl + 512 * DIMM;  R = DIMM; C = HD; }
  else if (blk < 4736) { local = blk - 4352; src = Wv;   dh = wqkvh + 1024 * DIMM; dl = wqkvl + 1024 * DIMM; R = DIMM; C = HD; }
  else if (blk < 5120) { local = blk - 4736; src = Wout; dh = woh;  dl = wol;  R = HD;  C = DIMM; }
  else                 { local = blk - 5120; src = Wrel; dh = wrh;  dl = wrl;  R = 192; C = HD; }
  const int ctiles = C / 32;
  const int c0 = (local % ctiles) * 32, r0 = (local / ctiles) * 32;
  {
    const int lr = t >> 3, lc = (t & 7) * 4;
    const float4 v = *(const float4*)&src[(size_t)(r0 + lr) * C + c0 + lc];
    tile[lr][lc] = v.x; tile[lr][lc + 1] = v.y; tile[lr][lc + 2] = v.z; tile[lr][lc + 3] = v.w;
  }
  __syncthreads();
  const int nn = t >> 3, kb = (t & 7) * 4;
  unsigned hb[4], lb[4];
#pragma unroll
  for (int e = 0; e < 4; e++) split2(tile[kb + e][nn], hb[e], lb[e]);
  const size_t o = (size_t)(c0 + nn) * R + r0 + kb;
  *(uint2*)&dh[o] = make_uint2(hb[0] | (hb[1] << 16), hb[2] | (hb[3] << 16));
  *(uint2*)&dl[o] = make_uint2(lb[0] | (lb[1] << 16), lb[2] | (lb[3] << 16));
}

// ---------------- 2. V transpose: vv [bh][s][64] -> vt [bh][64][2048] ----------------
__global__ void vtrans_kernel(const short* __restrict__ vv, short* __restrict__ vt) {
  __shared__ short tile[64][72];
  const int t = threadIdx.x;
  const int s0 = blockIdx.x * 64, bh = blockIdx.y;
  {
    const int sl = t >> 2, dc = (t & 3) * 16;
    const short* src = vv + ((size_t)bh * SEQ + s0 + sl) * DK + dc;
    *(uint4*)&tile[sl][dc]     = *(const uint4*)src;
    *(uint4*)&tile[sl][dc + 8] = *(const uint4*)(src + 8);
  }
  __syncthreads();
  const int dr = t >> 6, sc = t & 63;
#pragma unroll
  for (int it = 0; it < 16; it++) {
    const int d = it * 4 + dr;
    vt[((size_t)bh * DK + d) * SEQ + s0 + sc] = tile[sc][d];
  }
}

// ---------------- 3. unified qkv+relk GEMM, async global_load_lds staging ----------------
// grid 512: [0,384)=qkv (K=768), [384,512)=relk (K=192). 128x128 tile, BK=32.
// LDS unpadded [128][32] (64B rows) — required by global_load_lds; same 8-way
// b128 read windows as the padded layout (m97's layout at 874 TF).
__global__ __launch_bounds__(256) void gemm_qr(
    const short* __restrict__ xh, const short* __restrict__ xl,
    const short* __restrict__ wqkvh, const short* __restrict__ wqkvl,
    const short* __restrict__ eh, const short* __restrict__ el,
    const short* __restrict__ wrh, const short* __restrict__ wrl,
    const float* __restrict__ cb, const float* __restrict__ pb,
    bf16* __restrict__ oq, bf16* __restrict__ oqp,
    bf16* __restrict__ ok, bf16* __restrict__ ov,
    bf16* __restrict__ relk) {
  __shared__ short AsH[128][32];
  __shared__ short AsL[128][32];
  __shared__ short BsH[128][32];
  __shared__ short BsL[128][32];

  const int bx = blockIdx.x;
  const bool isq = bx < 384;
  const int lbx = isq ? bx : bx - 384;
  const int mt = lbx & 31, ntile = lbx >> 5;
  const int m0 = mt * 128, n0 = ntile * 128;
  const int KD = isq ? DIMM : 192;
  const short* Ah = isq ? xh : eh;
  const short* Al = isq ? xl : el;
  const short* Bh = isq ? wqkvh : wrh;
  const short* Bl = isq ? wqkvl : wrl;

  const int t = threadIdx.x, lane = t & 63, w = t >> 6;
  const int quad = lane >> 4, l15 = lane & 15;
  const int wm = (w >> 1) * 64, wn = (w & 1) * 64;

  // async staging: wave w covers rows [w*32, w*32+32), 2 calls (c=0,1)
  const int srow = w * 32 + (lane >> 2);   // + c*16
  const int skof = (lane & 3) * 8;         // shorts within 64B row

  f32x4 acc[4][4];
#pragma unroll
  for (int i = 0; i < 4; i++)
#pragma unroll
    for (int j = 0; j < 4; j++) acc[i][j] = (f32x4){0.f, 0.f, 0.f, 0.f};

  for (int k0 = 0; k0 < KD; k0 += 32) {
    __syncthreads();
#pragma unroll
    for (int c = 0; c < 2; c++) {
      const size_t ra = (size_t)(m0 + srow + c * 16) * KD + k0 + skof;
      const size_t rb = (size_t)(n0 + srow + c * 16) * KD + k0 + skof;
      short* la = &AsH[w * 32 + c * 16][0];
      cp16(&Ah[ra], la);
      cp16(&Al[ra], &AsL[w * 32 + c * 16][0]);
      cp16(&Bh[rb], &BsH[w * 32 + c * 16][0]);
      cp16(&Bl[rb], &BsL[w * 32 + c * 16][0]);
    }
    __syncthreads();   // drains vmcnt(0): async data landed

    short8 amh[4], aml[4], bnh[4], bnl[4];
#pragma unroll
    for (int i = 0; i < 4; i++) {
      amh[i] = *(const short8*)&AsH[wm + i * 16 + l15][quad * 8];
      aml[i] = *(const short8*)&AsL[wm + i * 16 + l15][quad * 8];
      bnh[i] = *(const short8*)&BsH[wn + i * 16 + l15][quad * 8];
      bnl[i] = *(const short8*)&BsL[wn + i * 16 + l15][quad * 8];
    }
#pragma unroll
    for (int i = 0; i < 4; i++) {
#pragma unroll
      for (int j = 0; j < 4; j++) {
        acc[i][j] = __builtin_amdgcn_mfma_f32_16x16x32_bf16(amh[i], bnh[j], acc[i][j], 0, 0, 0);
        acc[i][j] = __builtin_amdgcn_mfma_f32_16x16x32_bf16(amh[i], bnl[j], acc[i][j], 0, 0, 0);
        acc[i][j] = __builtin_amdgcn_mfma_f32_16x16x32_bf16(aml[i], bnh[j], acc[i][j], 0, 0, 0);
      }
    }
  }

  if (isq) {
    const int sel = ntile >> 2;   // 0=q,1=k,2=v
#pragma unroll
    for (int i = 0; i < 4; i++) {
#pragma unroll
      for (int j = 0; j < 4; j++) {
        const int n = n0 + wn + j * 16 + l15;
        const int hd_ = n & 511, hh = hd_ >> 6, d = hd_ & 63;
#pragma unroll
        for (int g = 0; g < 4; g++) {
          const int m = m0 + wm + i * 16 + quad * 4 + g;
          const int b = m >> 11, s = m & 2047;
          const size_t idx = (((size_t)(b * HEADS + hh) * SEQ) + s) * DK + d;
          const float v = acc[i][j][g];
          if (sel == 0) {
            const float sv = v * 0.125f;   // dk^-0.5
            oq[idx]  = __float2bfloat16(sv + cb[hh * DK + d]);
            oqp[idx] = __float2bfloat16(sv + pb[hh * DK + d]);
          } else if (sel == 1) {
            ok[idx] = __float2bfloat16(v);
          } else {
            ov[idx] = __float2bfloat16(v);
          }
        }
      }
    }
  } else {
#pragma unroll
    for (int i = 0; i < 4; i++) {
#pragma unroll
      for (int j = 0; j < 4; j++) {
        const int n = n0 + wn + j * 16 + l15;
        const int hh = n >> 6, d = n & 63;
#pragma unroll
        for (int g = 0; g < 4; g++) {
          const int m = m0 + wm + i * 16 + quad * 4 + g;
          if (m < NPOS) relk[((size_t)hh * NPOS + m) * DK + d] = __float2bfloat16(acc[i][j][g]);
        }
      }
    }
  }
}

// ---------------- 4. out-projection GEMM, async staging ----------------
__global__ __launch_bounds__(256) void out_gemm(
    const short* __restrict__ Ahp,
    const short* __restrict__ Bhp, const short* __restrict__ Blp,
    const float* __restrict__ bias, float* __restrict__ ofp) {
  __shared__ short AsH[128][32];
  __shared__ short BsH[128][32];
  __shared__ short BsL[128][32];

  const int t = threadIdx.x, lane = t & 63, w = t >> 6;
  const int quad = lane >> 4, l15 = lane & 15;
  const int wm = (w >> 1) * 64, wn = (w & 1) * 64;
  const int m0 = blockIdx.x * 128, n0 = blockIdx.y * 128;
  const int srow = w * 32 + (lane >> 2);
  const int skof = (lane & 3) * 8;

  f32x4 acc[4][4];
#pragma unroll
  for (int i = 0; i < 4; i++)
#pragma unroll
    for (int j = 0; j < 4; j++) acc[i][j] = (f32x4){0.f, 0.f, 0.f, 0.f};

  for (int k0 = 0; k0 < HD; k0 += 32) {
    __syncthreads();
#pragma unroll
    for (int c = 0; c < 2; c++) {
      const size_t ra = (size_t)(m0 + srow + c * 16) * HD + k0 + skof;
      const size_t rb = (size_t)(n0 + srow + c * 16) * HD + k0 + skof;
      cp16(&Ahp[ra], &AsH[w * 32 + c * 16][0]);
      cp16(&Bhp[rb], &BsH[w * 32 + c * 16][0]);
      cp16(&Blp[rb], &BsL[w * 32 + c * 16][0]);
    }
    __syncthreads();

    short8 amh[4], bnh[4], bnl[4];
#pragma unroll
    for (int i = 0; i < 4; i++) {
      amh[i] = *(const short8*)&AsH[wm + i * 16 + l15][quad * 8];
      bnh[i] = *(const short8*)&BsH[wn + i * 16 + l15][quad * 8];
      bnl[i] = *(const short8*)&BsL[wn + i * 16 + l15][quad * 8];
    }
#pragma unroll
    for (int i = 0; i < 4; i++) {
#pragma unroll
      for (int j = 0; j < 4; j++) {
        acc[i][j] = __builtin_amdgcn_mfma_f32_16x16x32_bf16(amh[i], bnh[j], acc[i][j], 0, 0, 0);
        acc[i][j] = __builtin_amdgcn_mfma_f32_16x16x32_bf16(amh[i], bnl[j], acc[i][j], 0, 0, 0);
      }
    }
  }

#pragma unroll
  for (int i = 0; i < 4; i++) {
#pragma unroll
    for (int j = 0; j < 4; j++) {
      const int n = n0 + wn + j * 16 + l15;
      const float bv = bias[n];
#pragma unroll
      for (int g = 0; g < 4; g++) {
        const int m = m0 + wm + i * 16 + quad * 4 + g;
        ofp[(size_t)m * DIMM + n] = acc[i][j][g] + bv;
      }
    }
  }
}

// ---------------- 5. no-max attention: LDS rel + LDS V^T staging (unchanged) ----------------
__global__ __launch_bounds__(256) void attn_mfma4(
    const short* __restrict__ qc, const short* __restrict__ qp,
    const short* __restrict__ kg, const short* __restrict__ vt,
    const short* __restrict__ relk,
    float* __restrict__ Op, float* __restrict__ Lp) {
  __shared__ short Rel_lds[128][72];     // block's rel window (128 rows)
  __shared__ short Vt_lds[64][72];       // V^T tile: [d][j]
  __shared__ short Pw[4][16][72];        // per-wave P in A-layout

  const int t    = threadIdx.x;
  const int lane = t & 63;
  const int w    = t >> 6;
  const int quad = lane >> 4;
  const int l15  = lane & 15;
  const int bh   = blockIdx.y;
  const int h    = bh & 7;
  const int i0   = blockIdx.x * 64;
  const int z    = blockIdx.z;
  const int jb   = z * (SEQ / 2);

  short8 qcA[2], qpA[2];
  {
    const size_t qrow = ((size_t)bh * SEQ + i0 + w * 16 + l15) * DK + quad * 8;
    qcA[0] = *(const short8*)(qc + qrow);
    qcA[1] = *(const short8*)(qc + qrow + 32);
    qpA[0] = *(const short8*)(qp + qrow);
    qpA[1] = *(const short8*)(qp + qrow + 32);
  }

  int idxg[4]; bool selg[4];
#pragma unroll
  for (int g = 0; g < 4; g++) {
    const int r = quad * 4 + g;
    idxg[g] = (((lane & 48) | ((l15 + 15 - r) & 15)) << 2);
    selg[g] = (l15 <= r);
  }

  short8 ones8;
#pragma unroll
  for (int e = 0; e < 8; e++) ones8[e] = (short)0x3F80;   // bf16 1.0

  f32x4 oacc[4];
#pragma unroll
  for (int dt = 0; dt < 4; dt++) oacc[dt] = (f32x4){0.f, 0.f, 0.f, 0.f};
  f32x4 lacc = (f32x4){0.f, 0.f, 0.f, 0.f};

  const short* kbase = kg + (size_t)bh * SEQ * DK;
  const short* vbase = vt + (size_t)bh * DK * SEQ;
  const short* rbase = relk + (size_t)h * NPOS * DK;

  const int rr  = t >> 1, rcc = (t & 1) * 32;
  const int vr  = t >> 2, vcc = (t & 3) * 16;
  const int rb_w = 48 - 16 * w;

  for (int jt = 0; jt < SEQ / 2 / 64; jt++) {
    const int j0 = jb + jt * 64;

    __syncthreads();
    {
      const short* src = rbase + (size_t)((j0 - i0 + 1984) + rr) * DK + rcc;
      *(uint4*)&Rel_lds[rr][rcc]      = *(const uint4*)(src);
      *(uint4*)&Rel_lds[rr][rcc + 8]  = *(const uint4*)(src + 8);
      *(uint4*)&Rel_lds[rr][rcc + 16] = *(const uint4*)(src + 16);
      *(uint4*)&Rel_lds[rr][rcc + 24] = *(const uint4*)(src + 24);
    }
    {
      const short* src = vbase + (size_t)vr * SEQ + j0 + vcc;
      *(uint4*)&Vt_lds[vr][vcc]     = *(const uint4*)(src);
      *(uint4*)&Vt_lds[vr][vcc + 8] = *(const uint4*)(src + 8);
    }
    __syncthreads();

    f32x4 sacc[4];
#pragma unroll
    for (int nt = 0; nt < 4; nt++) {
      const short* kr = kbase + (size_t)(j0 + nt * 16 + l15) * DK + quad * 8;
      short8 b0 = *(const short8*)kr;
      short8 b1 = *(const short8*)(kr + 32);
      f32x4 a = (f32x4){0.f, 0.f, 0.f, 0.f};
      a = __builtin_amdgcn_mfma_f32_16x16x32_bf16(qcA[0], b0, a, 0, 0, 0);
      a = __builtin_amdgcn_mfma_f32_16x16x32_bf16(qcA[1], b1, a, 0, 0, 0);
      sacc[nt] = a;
    }

    f32x4 rprev;
    {
      const short* rl = &Rel_lds[rb_w + l15][quad * 8];
      short8 b0 = *(const short8*)rl;
      short8 b1 = *(const short8*)(rl + 32);
      f32x4 a = (f32x4){0.f, 0.f, 0.f, 0.f};
      a = __builtin_amdgcn_mfma_f32_16x16x32_bf16(qpA[0], b0, a, 0, 0, 0);
      a = __builtin_amdgcn_mfma_f32_16x16x32_bf16(qpA[1], b1, a, 0, 0, 0);
      rprev = a;
    }
    f32x4 bpp;
#pragma unroll
    for (int g = 0; g < 4; g++)
      bpp[g] = __int_as_float(__builtin_amdgcn_ds_bpermute(idxg[g], __float_as_int(rprev[g])));

#pragma unroll
    for (int nt = 0; nt < 4; nt++) {
      f32x4 rcur;
      {
        const short* rl = &Rel_lds[rb_w + (nt + 1) * 16 + l15][quad * 8];
        short8 b0 = *(const short8*)rl;
        short8 b1 = *(const short8*)(rl + 32);
        f32x4 a = (f32x4){0.f, 0.f, 0.f, 0.f};
        a = __builtin_amdgcn_mfma_f32_16x16x32_bf16(qpA[0], b0, a, 0, 0, 0);
        a = __builtin_amdgcn_mfma_f32_16x16x32_bf16(qpA[1], b1, a, 0, 0, 0);
        rcur = a;
      }
      f32x4 bpc;
#pragma unroll
      for (int g = 0; g < 4; g++)
        bpc[g] = __int_as_float(__builtin_amdgcn_ds_bpermute(idxg[g], __float_as_int(rcur[g])));
#pragma unroll
      for (int g = 0; g < 4; g++) {
        const float relv = selg[g] ? bpp[g] : bpc[g];
        const float s = sacc[nt][g] + relv;
        const float p = __expf(s - 12.0f);
        Pw[w][quad * 4 + g][nt * 16 + l15] = (short)f2bf(p);
      }
      bpp = bpc;
    }

#pragma unroll
    for (int ks = 0; ks < 2; ks++) {
      short8 pA = *(const short8*)&Pw[w][l15][ks * 32 + quad * 8];
      lacc = __builtin_amdgcn_mfma_f32_16x16x32_bf16(pA, ones8, lacc, 0, 0, 0);
#pragma unroll
      for (int dt = 0; dt < 4; dt++) {
        short8 vB = *(const short8*)&Vt_lds[dt * 16 + l15][ks * 32 + quad * 8];
        oacc[dt] = __builtin_amdgcn_mfma_f32_16x16x32_bf16(pA, vB, oacc[dt], 0, 0, 0);
      }
    }
  }

  const size_t obase = ((size_t)(z * BH + bh) * SEQ + i0 + w * 16);
#pragma unroll
  for (int g = 0; g < 4; g++) {
    const int r = quad * 4 + g;
#pragma unroll
    for (int dt = 0; dt < 4; dt++)
      Op[(obase + r) * DK + dt * 16 + l15] = oacc[dt][g];
    if (l15 == 0) Lp[obase + r] = lacc[g];
  }
}

// ---------------- 6. merge halves -> oh bf16 ----------------
__global__ void merge_kernel(const float* __restrict__ Op, const float* __restrict__ Lp,
                             bf16* __restrict__ oh) {
  const int gid = blockIdx.x * 256 + threadIdx.x;
  const int m = gid >> 7;
  const int n0 = (gid & 127) * 4;
  const int b = m >> 11, s = m & 2047;
  const int hh = n0 >> 6, d0 = n0 & 63;
  const int bh = b * HEADS + hh;
  const float l = Lp[(size_t)bh * SEQ + s] + Lp[((size_t)BH + bh) * SEQ + s];
  const float inv = 1.0f / l;
  const float4 o0 = *(const float4*)&Op[((size_t)bh * SEQ + s) * DK + d0];
  const float4 o1 = *(const float4*)&Op[(((size_t)BH + bh) * SEQ + s) * DK + d0];
  *(uint2*)&oh[(size_t)m * HD + n0] = make_uint2(
      f2bf((o0.x + o1.x) * inv) | (f2bf((o0.y + o1.y) * inv) << 16),
      f2bf((o0.z + o1.z) * inv) | (f2bf((o0.w + o1.w) * inv) << 16));
}

// ---------------- launch ----------------
extern "C" void kernel_launch(void* const* d_in, const int* in_sizes, int n_in,
                              void* d_out, int out_size, void* d_ws, size_t ws_size,
                              hipStream_t stream) {
  (void)in_sizes; (void)n_in; (void)out_size; (void)ws_size;
  const float* x    = (const float*)d_in[0];
  const float* Wq   = (const float*)d_in[1];
  const float* Wk   = (const float*)d_in[2];
  const float* Wv   = (const float*)d_in[3];
  const float* Wrel = (const float*)d_in[4];
  const float* Wout = (const float*)d_in[5];
  const float* bout = (const float*)d_in[6];
  const float* cb   = (const float*)d_in[7];
  const float* pb   = (const float*)d_in[8];
  float* out = (float*)d_out;

  char* ws = (char*)d_ws;
  bf16*  relk = (bf16*)(ws + OB_RELK);
  bf16*  qc   = (bf16*)(ws + OB_QC);
  bf16*  qp   = (bf16*)(ws + OB_QP);
  bf16*  kk   = (bf16*)(ws + OB_K);
  bf16*  vv   = (bf16*)(ws + OB_V);
  bf16*  oh   = (bf16*)(ws + OB_OH);
  short* vt   = (short*)(ws + OB_VT);
  float* Opb  = (float*)(ws + OB_OP);
  float* Lpb  = (float*)(ws + OB_LP);
  short* embh = (short*)(ws + OB_EMBH);
  short* embl = (short*)(ws + OB_EMBL);
  short* xh   = (short*)(ws + OB_XH);
  short* xl   = (short*)(ws + OB_XL);
  short* wqh  = (short*)(ws + OB_WQKVH);
  short* wql  = (short*)(ws + OB_WQKVL);
  short* woh  = (short*)(ws + OB_WOH);
  short* wol  = (short*)(ws + OB_WOL);
  short* wrh  = (short*)(ws + OB_WRH);
  short* wrl  = (short*)(ws + OB_WRL);

  hipLaunchKernelGGL(prep_all, dim3(5216), dim3(256), 0, stream,
                     x, Wq, Wk, Wv, Wout, Wrel,
                     embh, embl, xh, xl, wqh, wql, woh, wol, wrh, wrl);
  hipLaunchKernelGGL(gemm_qr, dim3(512), dim3(256), 0, stream,
                     xh, xl, wqh, wql, embh, embl, wrh, wrl,
                     cb, pb, qc, qp, kk, vv, relk);
  hipLaunchKernelGGL(vtrans_kernel, dim3(SEQ / 64, BH), dim3(256), 0, stream,
                     (const short*)vv, vt);
  hipLaunchKernelGGL(attn_mfma4, dim3(SEQ / 64, BH, 2), dim3(256), 0, stream,
                     (const short*)qc, (const short*)qp, (const short*)kk,
                     (const short*)vt, (const short*)relk, Opb, Lpb);
  hipLaunchKernelGGL(merge_kernel, dim3(ROWS * (HD / 4) / 256), dim3(256), 0, stream,
                     Opb, Lpb, oh);
  hipLaunchKernelGGL(out_gemm, dim3(32, 6), dim3(256), 0, stream,
                     (const short*)oh, woh, wol, bout, out);
}